// Round 2
// baseline (232.420 us; speedup 1.0000x reference)
//
#include <hip/hip_runtime.h>
#include <hip/hip_bf16.h>

// MultiBertAttention fp32 I/O, bf16 MFMA internals.
// R11: attn_kernel is LDS-read-BW bound (512KB LDS reads per CU per key-tile:
//      every wave re-reads the full K and V tiles). Fix: each wave owns TWO
//      16-q groups (32 q) -> every K/V LDS fragment feeds 2 MFMAs; block is
//      4 waves (256 thr) covering the same 128-q tile -> per-CU LDS traffic
//      halved. Layouts/swizzles/staging identical to R10 (verified).
//      prep / gemm_qkvt / gemm_out unchanged.

typedef unsigned short u16;

#define D_MODEL 1024
#define NHEAD 16
#define HDIM 64
#define BATCH 2
#define SEQ 2048
#define MTOT (BATCH * SEQ)  // 4096

#define QSCALE 0.18033688011112042f  // (1/8) * log2(e)

using frag_ab = __attribute__((ext_vector_type(8))) short;  // 8 bf16 (16x16x32 A/B)
using frag_s4 = __attribute__((ext_vector_type(4))) short;  // 4 bf16 (16x16x16 A/B)
using frag_cd = __attribute__((ext_vector_type(4))) float;  // 4 fp32

__device__ __forceinline__ u16 f2u(float f) {  // RNE fp32->bf16
    union { float f; unsigned int i; } x;
    x.f = f;
    unsigned int r = x.i + 0x7fffu + ((x.i >> 16) & 1u);
    return (u16)(r >> 16);
}
__device__ __forceinline__ unsigned int pkrn(float a, float b) {  // v_cvt_pk_bf16_f32
    union { __hip_bfloat162 h; unsigned int u; } c;
    c.h = __float22bfloat162_rn(float2{a, b});
    return c.u;
}

// ---------------------------------------------------------------------------
// prep: z<4 -> Wt[z][n][k] = bf16(W_z[k][n]); z==4 -> xb = bf16(x).
// ---------------------------------------------------------------------------
__global__ void prep(const float* __restrict__ W0, const float* __restrict__ W1,
                     const float* __restrict__ W2, const float* __restrict__ W3,
                     const float* __restrict__ X, u16* __restrict__ Wt,
                     u16* __restrict__ Xb) {
    const int z = blockIdx.z;
    const int tx = threadIdx.x, ty = threadIdx.y;
    if (z < 4) {
        __shared__ u16 t[32][33];
        const float* W = (z == 0) ? W0 : (z == 1) ? W1 : (z == 2) ? W2 : W3;
        u16* o = Wt + (size_t)z * D_MODEL * D_MODEL;
        int n0 = blockIdx.x * 32, k0 = blockIdx.y * 32;
        #pragma unroll
        for (int i = ty; i < 32; i += 8) t[i][tx] = f2u(W[(size_t)(k0 + i) * D_MODEL + n0 + tx]);
        __syncthreads();
        #pragma unroll
        for (int i = ty; i < 32; i += 8) o[(size_t)(n0 + i) * D_MODEL + k0 + tx] = t[tx][i];
    } else {
        int tid = ty * 32 + tx;
        size_t base = ((size_t)(blockIdx.y * 32 + blockIdx.x) * 256 + tid) * 16;
        #pragma unroll
        for (int c = 0; c < 4; ++c) {
            float4 v = *(const float4*)&X[base + c * 4];
            ushort4 o;
            o.x = f2u(v.x); o.y = f2u(v.y); o.z = f2u(v.z); o.w = f2u(v.w);
            *(ushort4*)&Xb[base + c * 4] = o;
        }
    }
}

// ---------------------------------------------------------------------------
// Fused QKV + V^T GEMM, 768 blocks (1D). 128x128 tile, BK=64, global_load_lds.
// ---------------------------------------------------------------------------
__launch_bounds__(256, 3)
__global__ void gemm_qkvt(const u16* __restrict__ xb, const u16* __restrict__ Wt,
                          const float* __restrict__ bq, const float* __restrict__ bk,
                          const float* __restrict__ bv, u16* __restrict__ QKw,
                          u16* __restrict__ Vtw) {
    constexpr int BK = 64;
    __shared__ __attribute__((aligned(16))) u16 As[128 * BK];
    __shared__ __attribute__((aligned(16))) u16 Bs[128 * BK];

    const int tid = threadIdx.x;
    const int w = tid >> 6;
    const int lane = tid & 63;
    const int lrow = lane & 15, lquad = lane >> 4;
    const size_t WSZ = (size_t)D_MODEL * D_MODEL;

    const int bid = blockIdx.x;
    const bool vt = bid >= 512;
    const int z = vt ? 2 : (bid >> 8);
    const int t = vt ? (bid - 512) : (bid & 255);
    const int n0 = vt ? (t & 31) * 128 : (t & 7) * 128;
    const int m0 = vt ? (t >> 5) * 128 : (t >> 3) * 128;
    const u16* Ap = vt ? (Wt + 2 * WSZ) : xb;
    const u16* Bp = vt ? xb : (Wt + (size_t)z * WSZ);
    const float* bias = vt ? bv : (z ? bk : bq);

    frag_cd acc[4][4];
    #pragma unroll
    for (int i = 0; i < 4; i++)
        #pragma unroll
        for (int j = 0; j < 4; j++) acc[i][j] = (frag_cd){0.f, 0.f, 0.f, 0.f};

    const int wm = (w >> 1) * 64, wn = (w & 1) * 64;

    for (int k0 = 0; k0 < D_MODEL; k0 += BK) {
        __syncthreads();
        #pragma unroll
        for (int it = 0; it < 4; ++it) {
            int c = it * 256 + tid;
            int r = c >> 3, c8 = c & 7;
            const u16* ga = Ap + (size_t)(m0 + r) * D_MODEL + k0 + c8 * 8;
            char* la = (char*)As + (it * 256 + w * 64) * 16;
            __builtin_amdgcn_global_load_lds((const __attribute__((address_space(1))) void*)ga,
                                             (__attribute__((address_space(3))) void*)la, 16, 0, 0);
            const u16* gb = Bp + (size_t)(n0 + r) * D_MODEL + k0 + c8 * 8;
            char* lb = (char*)Bs + (it * 256 + w * 64) * 16;
            __builtin_amdgcn_global_load_lds((const __attribute__((address_space(1))) void*)gb,
                                             (__attribute__((address_space(3))) void*)lb, 16, 0, 0);
        }
        __syncthreads();

        #pragma unroll
        for (int kc = 0; kc < 2; ++kc) {
            frag_ab av[4], bvv[4];
            #pragma unroll
            for (int i = 0; i < 4; i++)
                av[i] = *(const frag_ab*)&As[(wm + i * 16 + lrow) * BK + kc * 32 + lquad * 8];
            #pragma unroll
            for (int j = 0; j < 4; j++)
                bvv[j] = *(const frag_ab*)&Bs[(wn + j * 16 + lrow) * BK + kc * 32 + lquad * 8];
            #pragma unroll
            for (int i = 0; i < 4; i++)
                #pragma unroll
                for (int j = 0; j < 4; j++)
                    acc[i][j] = __builtin_amdgcn_mfma_f32_16x16x32_bf16(av[i], bvv[j], acc[i][j], 0, 0, 0);
        }
    }

    const float scale = (!vt && z == 0) ? QSCALE : 1.0f;
    #pragma unroll
    for (int j = 0; j < 4; j++) {
        int gn = n0 + wn + j * 16 + lrow;
        #pragma unroll
        for (int i = 0; i < 4; i++) {
            #pragma unroll
            for (int rr = 0; rr < 4; ++rr) {
                int gm = m0 + wm + i * 16 + lquad * 4 + rr;
                if (!vt) {
                    float v = (acc[i][j][rr] + bias[gn]) * scale;
                    u16* oz = QKw + (size_t)z * ((size_t)MTOT * D_MODEL);
                    int b = gm >> 11, s = gm & (SEQ - 1);
                    int h = gn >> 6, d = gn & (HDIM - 1);
                    oz[(((size_t)(b * NHEAD + h)) * SEQ + s) * HDIM + d] = f2u(v);
                } else {
                    float v = acc[i][j][rr] + bias[gm];
                    int h = gm >> 6, d = gm & (HDIM - 1);
                    int b = gn >> 11, s = gn & (SEQ - 1);
                    Vtw[(((size_t)(b * NHEAD + h)) * HDIM + d) * SEQ + s] = f2u(v);
                }
            }
        }
    }
}

// ---------------------------------------------------------------------------
// Out projection: 64x128 tile (512 blocks), fp32 store.
// ---------------------------------------------------------------------------
__launch_bounds__(256, 2)
__global__ void gemm_out(const u16* __restrict__ A, const u16* __restrict__ Wt,
                         const float* __restrict__ bias, float* __restrict__ out) {
    constexpr int BK = 64;
    __shared__ __attribute__((aligned(16))) u16 As[64 * BK];
    __shared__ __attribute__((aligned(16))) u16 Bs[128 * BK];

    const int tid = threadIdx.x;
    const int w = tid >> 6;
    const int lane = tid & 63;
    const int lrow = lane & 15, lquad = lane >> 4;
    const int m0 = blockIdx.y * 64, n0 = blockIdx.x * 128;

    frag_cd acc[2][4];
    #pragma unroll
    for (int i = 0; i < 2; i++)
        #pragma unroll
        for (int j = 0; j < 4; j++) acc[i][j] = (frag_cd){0.f, 0.f, 0.f, 0.f};

    const int wm = (w >> 1) * 32, wn = (w & 1) * 64;

    for (int k0 = 0; k0 < D_MODEL; k0 += BK) {
        __syncthreads();
        #pragma unroll
        for (int it = 0; it < 2; ++it) {
            int c = it * 256 + tid;
            int r = c >> 3, c8 = c & 7;
            const u16* ga = A + (size_t)(m0 + r) * D_MODEL + k0 + c8 * 8;
            char* la = (char*)As + (it * 256 + w * 64) * 16;
            __builtin_amdgcn_global_load_lds((const __attribute__((address_space(1))) void*)ga,
                                             (__attribute__((address_space(3))) void*)la, 16, 0, 0);
        }
        #pragma unroll
        for (int it = 0; it < 4; ++it) {
            int c = it * 256 + tid;
            int r = c >> 3, c8 = c & 7;
            const u16* gb = Wt + (size_t)(n0 + r) * D_MODEL + k0 + c8 * 8;
            char* lb = (char*)Bs + (it * 256 + w * 64) * 16;
            __builtin_amdgcn_global_load_lds((const __attribute__((address_space(1))) void*)gb,
                                             (__attribute__((address_space(3))) void*)lb, 16, 0, 0);
        }
        __syncthreads();

        #pragma unroll
        for (int kc = 0; kc < 2; ++kc) {
            frag_ab av[2], bvv[4];
            #pragma unroll
            for (int i = 0; i < 2; i++)
                av[i] = *(const frag_ab*)&As[(wm + i * 16 + lrow) * BK + kc * 32 + lquad * 8];
            #pragma unroll
            for (int j = 0; j < 4; j++)
                bvv[j] = *(const frag_ab*)&Bs[(wn + j * 16 + lrow) * BK + kc * 32 + lquad * 8];
            #pragma unroll
            for (int i = 0; i < 2; i++)
                #pragma unroll
                for (int j = 0; j < 4; j++)
                    acc[i][j] = __builtin_amdgcn_mfma_f32_16x16x32_bf16(av[i], bvv[j], acc[i][j], 0, 0, 0);
        }
    }

    #pragma unroll
    for (int j = 0; j < 4; j++) {
        int gn = n0 + wn + j * 16 + lrow;
        float bvf = bias[gn];
        #pragma unroll
        for (int i = 0; i < 2; i++)
            #pragma unroll
            for (int rr = 0; rr < 4; ++rr) {
                int gm = m0 + wm + i * 16 + lquad * 4 + rr;
                out[(size_t)gm * D_MODEL + gn] = acc[i][j][rr] + bvf;
            }
    }
}

// ---------------------------------------------------------------------------
// Attention (transposed, register-resident P). Grid (16,32), 256 thr (4 waves,
// each owning TWO 16-q groups = 32 q). S^T = K.Q^T via mfma_16x16x32; p = exp2
// in regs; P packed (v_cvt_pk_bf16_f32) feeds PV (O^T = V^T.P^T) via
// mfma_16x16x16 B-operand. Every K/V LDS fragment feeds 2 MFMAs (one per
// q-group) -> per-CU LDS read traffic halved vs R10 (the measured bottleneck).
// K/V staged via global_load_lds (16B), double-buffered, prefetch before
// compute; XOR chunk swizzle on the GLOBAL source + same XOR on reads
// (conflict-free b128 K / b64 V). LDS: 2*(128x64) K + 2*(64x128) V = 64 KB
// -> 2 blocks/CU (grid 512 = 2/CU).
// ---------------------------------------------------------------------------
__launch_bounds__(256, 2)
__global__ void attn_kernel(const u16* __restrict__ Q, const u16* __restrict__ K,
                            const u16* __restrict__ Vt, u16* __restrict__ O) {
    __shared__ __attribute__((aligned(16))) u16 Ks[2][128 * 64];
    __shared__ __attribute__((aligned(16))) u16 Vs[2][64 * 128];

    const int tid = threadIdx.x;
    const int w = tid >> 6;           // 4 waves
    const int lane = tid & 63;
    const int lrow = lane & 15, lquad = lane >> 4;
    const int bh = blockIdx.y;
    const int q0 = blockIdx.x * 128;
    const size_t base = (size_t)bh * SEQ * HDIM;
    const u16* Qg = Q + base;
    const u16* Kg = K + base;
    const u16* Vg = Vt + base;  // [d][s]

    // Two q-groups per wave: rows q0 + g*64 + w*16 + lrow
    frag_ab qf[2][2];
    #pragma unroll
    for (int g = 0; g < 2; ++g)
        #pragma unroll
        for (int kc = 0; kc < 2; ++kc)
            qf[g][kc] = *(const frag_ab*)&Qg[(size_t)(q0 + g * 64 + w * 16 + lrow) * HDIM + kc * 32 + lquad * 8];

    frag_cd accOT[2][4];   // [group][df]: O^T lane q = lrow, d = df*16 + lquad*4 + i
    #pragma unroll
    for (int g = 0; g < 2; ++g)
        #pragma unroll
        for (int df = 0; df < 4; df++) accOT[g][df] = (frag_cd){0.f, 0.f, 0.f, 0.f};
    float lacc[2] = {0.f, 0.f};   // per-lane softmax denom partials

    // --- staging: global_load_lds, pre-swizzled global source, linear LDS dest
    auto stage = [&](int bsel, int kt2) {
        const u16* Kt = Kg + (size_t)(kt2 * 128) * HDIM;
        #pragma unroll
        for (int it = 0; it < 4; ++it) {
            const int c = it * 256 + tid;
            // K: row rk (128), 16B chunk ck of 8; source chunk = ck ^ (rk&7)
            const int rk = c >> 3, ck = c & 7;
            const u16* gk = Kt + rk * HDIM + ((ck ^ (rk & 7)) << 3);
            char* lk = (char*)&Ks[bsel][0] + (it * 256 + w * 64) * 16;
            __builtin_amdgcn_global_load_lds((const __attribute__((address_space(1))) void*)gk,
                                             (__attribute__((address_space(3))) void*)lk, 16, 0, 0);
            // V^T: row d=rv (64), 16B chunk gv of 16; source chunk = gv ^ (rv&7)
            const int rv = c >> 4, gv = c & 15;
            const u16* gvp = Vg + (size_t)rv * SEQ + kt2 * 128 + ((gv ^ (rv & 7)) << 3);
            char* lv = (char*)&Vs[bsel][0] + (it * 256 + w * 64) * 16;
            __builtin_amdgcn_global_load_lds((const __attribute__((address_space(1))) void*)gvp,
                                             (__attribute__((address_space(3))) void*)lv, 16, 0, 0);
        }
    };

    stage(0, 0);
    __syncthreads();   // compiler drains vmcnt(0) before barrier

    int buf = 0;
    for (int kt = 0; kt < SEQ / 128; ++kt) {
        if (kt + 1 < SEQ / 128) stage(buf ^ 1, kt + 1);  // prefetch next tile

        const u16* Ksb = &Ks[buf][0];
        const u16* Vsb = &Vs[buf][0];

        // S^T[key][q] per group: A = K (m=key), B = Q. Each K fragment -> 2 MFMAs.
        frag_cd sc[2][8];
        #pragma unroll
        for (int g = 0; g < 2; ++g)
            #pragma unroll
            for (int mf = 0; mf < 8; mf++) sc[g][mf] = (frag_cd){0.f, 0.f, 0.f, 0.f};
        #pragma unroll
        for (int kc = 0; kc < 2; ++kc) {
            const int cswz = (((kc << 2) + lquad) ^ (lrow & 7)) << 3;  // swizzled k-chunk (u16)
            #pragma unroll
            for (int mf = 0; mf < 8; mf++) {
                frag_ab kf = *(const frag_ab*)&Ksb[(mf * 16 + lrow) * 64 + cswz];
                sc[0][mf] = __builtin_amdgcn_mfma_f32_16x16x32_bf16(kf, qf[0][kc], sc[0][mf], 0, 0, 0);
                sc[1][mf] = __builtin_amdgcn_mfma_f32_16x16x32_bf16(kf, qf[1][kc], sc[1][mf], 0, 0, 0);
            }
        }

        // p = 2^s in-register; per-lane rowsum partials; pack via v_cvt_pk_bf16_f32
        frag_s4 pk[2][8];
        #pragma unroll
        for (int g = 0; g < 2; ++g)
            #pragma unroll
            for (int mf = 0; mf < 8; mf++) {
                float e0 = exp2f(sc[g][mf][0]), e1 = exp2f(sc[g][mf][1]);
                float e2 = exp2f(sc[g][mf][2]), e3 = exp2f(sc[g][mf][3]);
                lacc[g] += (e0 + e1) + (e2 + e3);
                union { frag_s4 s; unsigned int u[2]; } pu;
                pu.u[0] = pkrn(e0, e1);
                pu.u[1] = pkrn(e2, e3);
                pk[g][mf] = pu.s;
            }

        // O^T += V^T . P^T : A = V^T (m=d, swizzled b64 from Vs) -> 2 MFMAs each
        #pragma unroll
        for (int mf = 0; mf < 8; mf++) {
            const int gc = 2 * mf + (lquad >> 1);
            #pragma unroll
            for (int df = 0; df < 4; df++) {
                const int dr = df * 16 + lrow;
                frag_s4 vf = *(const frag_s4*)&Vsb[dr * 128 + ((gc ^ (lrow & 7)) << 3) + (lquad & 1) * 4];
                accOT[0][df] = __builtin_amdgcn_mfma_f32_16x16x16bf16_1k(vf, pk[0][mf], accOT[0][df], 0, 0, 0);
                accOT[1][df] = __builtin_amdgcn_mfma_f32_16x16x16bf16_1k(vf, pk[1][mf], accOT[1][df], 0, 0, 0);
            }
        }

        __syncthreads();   // drains prefetch vmcnt + protects buf swap
        buf ^= 1;
    }

    // reduce rowsums across the 4 quads holding each q
    #pragma unroll
    for (int g = 0; g < 2; ++g) {
        lacc[g] += __shfl_xor(lacc[g], 16);
        lacc[g] += __shfl_xor(lacc[g], 32);
    }

    // epilogue: lane owns one q per group -> single reciprocal; b64 stores
    const int b = bh >> 4, h = bh & (NHEAD - 1);
    #pragma unroll
    for (int g = 0; g < 2; ++g) {
        const int s = q0 + g * 64 + w * 16 + lrow;
        const float inv = 1.0f / lacc[g];
        u16* orow = O + ((size_t)(b * SEQ + s)) * D_MODEL + h * HDIM;
        #pragma unroll
        for (int df = 0; df < 4; df++) {
            union { unsigned int u[2]; ushort4 s4; } o;
            o.u[0] = pkrn(accOT[g][df][0] * inv, accOT[g][df][1] * inv);
            o.u[1] = pkrn(accOT[g][df][2] * inv, accOT[g][df][3] * inv);
            *(ushort4*)&orow[df * 16 + lquad * 4] = o.s4;
        }
    }
}

// ---------------------------------------------------------------------------
// Workspace (u16 elems): xb [0,4M) | Wt 4 slabs [4M,8M) | Q,K [8M,16M)
//                        Vt [16M,20M) | attn-out [20M,24M)   = 48 MB
// ---------------------------------------------------------------------------
extern "C" void kernel_launch(void* const* d_in, const int* in_sizes, int n_in,
                              void* d_out, int out_size, void* d_ws, size_t ws_size,
                              hipStream_t stream) {
    const float* x  = (const float*)d_in[0];
    const float* Wq = (const float*)d_in[1];
    const float* bq = (const float*)d_in[2];
    const float* Wk = (const float*)d_in[3];
    const float* bk = (const float*)d_in[4];
    const float* Wv = (const float*)d_in[5];
    const float* bv = (const float*)d_in[6];
    const float* Wo = (const float*)d_in[7];
    const float* bo = (const float*)d_in[8];

    u16* ws = (u16*)d_ws;
    const size_t WSZ = (size_t)D_MODEL * D_MODEL;    // 1M elems
    const size_t TSZ = (size_t)MTOT * D_MODEL;       // 4M elems
    u16* xb  = ws;
    u16* Wt  = ws + 4 * WSZ;
    u16* QKw = ws + 8 * WSZ;        // Q slab 0, K slab 1
    u16* Vtw = QKw + 2 * TSZ;
    u16* Aw  = Vtw + TSZ;

    prep<<<dim3(32, 32, 5), dim3(32, 8), 0, stream>>>(Wq, Wk, Wv, Wo, x, Wt, xb);
    gemm_qkvt<<<dim3(768), 256, 0, stream>>>(xb, Wt, bq, bk, bv, QKw, Vtw);
    attn_kernel<<<dim3(16, 32), 256, 0, stream>>>(QKw, QKw + TSZ, Vtw, Aw);
    gemm_out<<<dim3(8, 64), 256, 0, stream>>>(Aw, Wt + 3 * WSZ, bo, (float*)d_out);
}

// Round 3
// 222.965 us; speedup vs baseline: 1.0424x; 1.0424x over previous
//
#include <hip/hip_runtime.h>
#include <hip/hip_bf16.h>

// MultiBertAttention fp32 I/O, bf16 MFMA internals.
// R12: attn_kernel is LATENCY-bound (R9/R10 @16 waves/CU = 76us; R11 @8 = 92us;
//      LDS-BW halving did nothing). Fix: raise occupancy to 32 waves/CU:
//      q-tile 64 -> grid 1024 blocks (4/CU), 512 thr, waves key-split (waves
//      0-3 keys [0,64), waves 4-7 keys [64,128) of each staged 128-key tile;
//      partial O^T/rowsum combined additively via LDS at the end (no max
//      subtraction -> partials sum exactly). Single-buffered 32KB LDS (R9
//      showed dbuf buys nothing), chunked compute to keep VGPR <= 64 for
//      8 waves/SIMD. Rowsum via packed f32x2 adds (v_pk_add_f32).
//      prep / gemm_qkvt / gemm_out unchanged.

typedef unsigned short u16;

#define D_MODEL 1024
#define NHEAD 16
#define HDIM 64
#define BATCH 2
#define SEQ 2048
#define MTOT (BATCH * SEQ)  // 4096

#define QSCALE 0.18033688011112042f  // (1/8) * log2(e)

using frag_ab = __attribute__((ext_vector_type(8))) short;  // 8 bf16 (16x16x32 A/B)
using frag_s4 = __attribute__((ext_vector_type(4))) short;  // 4 bf16 (16x16x16 A/B)
using frag_cd = __attribute__((ext_vector_type(4))) float;  // 4 fp32
using f32x2   = __attribute__((ext_vector_type(2))) float;

__device__ __forceinline__ u16 f2u(float f) {  // RNE fp32->bf16
    union { float f; unsigned int i; } x;
    x.f = f;
    unsigned int r = x.i + 0x7fffu + ((x.i >> 16) & 1u);
    return (u16)(r >> 16);
}
__device__ __forceinline__ unsigned int pkrn(float a, float b) {  // v_cvt_pk_bf16_f32
    union { __hip_bfloat162 h; unsigned int u; } c;
    c.h = __float22bfloat162_rn(float2{a, b});
    return c.u;
}

// ---------------------------------------------------------------------------
// prep: z<4 -> Wt[z][n][k] = bf16(W_z[k][n]); z==4 -> xb = bf16(x).
// ---------------------------------------------------------------------------
__global__ void prep(const float* __restrict__ W0, const float* __restrict__ W1,
                     const float* __restrict__ W2, const float* __restrict__ W3,
                     const float* __restrict__ X, u16* __restrict__ Wt,
                     u16* __restrict__ Xb) {
    const int z = blockIdx.z;
    const int tx = threadIdx.x, ty = threadIdx.y;
    if (z < 4) {
        __shared__ u16 t[32][33];
        const float* W = (z == 0) ? W0 : (z == 1) ? W1 : (z == 2) ? W2 : W3;
        u16* o = Wt + (size_t)z * D_MODEL * D_MODEL;
        int n0 = blockIdx.x * 32, k0 = blockIdx.y * 32;
        #pragma unroll
        for (int i = ty; i < 32; i += 8) t[i][tx] = f2u(W[(size_t)(k0 + i) * D_MODEL + n0 + tx]);
        __syncthreads();
        #pragma unroll
        for (int i = ty; i < 32; i += 8) o[(size_t)(n0 + i) * D_MODEL + k0 + tx] = t[tx][i];
    } else {
        int tid = ty * 32 + tx;
        size_t base = ((size_t)(blockIdx.y * 32 + blockIdx.x) * 256 + tid) * 16;
        #pragma unroll
        for (int c = 0; c < 4; ++c) {
            float4 v = *(const float4*)&X[base + c * 4];
            ushort4 o;
            o.x = f2u(v.x); o.y = f2u(v.y); o.z = f2u(v.z); o.w = f2u(v.w);
            *(ushort4*)&Xb[base + c * 4] = o;
        }
    }
}

// ---------------------------------------------------------------------------
// Fused QKV + V^T GEMM, 768 blocks (1D). 128x128 tile, BK=64, global_load_lds.
// ---------------------------------------------------------------------------
__launch_bounds__(256, 3)
__global__ void gemm_qkvt(const u16* __restrict__ xb, const u16* __restrict__ Wt,
                          const float* __restrict__ bq, const float* __restrict__ bk,
                          const float* __restrict__ bv, u16* __restrict__ QKw,
                          u16* __restrict__ Vtw) {
    constexpr int BK = 64;
    __shared__ __attribute__((aligned(16))) u16 As[128 * BK];
    __shared__ __attribute__((aligned(16))) u16 Bs[128 * BK];

    const int tid = threadIdx.x;
    const int w = tid >> 6;
    const int lane = tid & 63;
    const int lrow = lane & 15, lquad = lane >> 4;
    const size_t WSZ = (size_t)D_MODEL * D_MODEL;

    const int bid = blockIdx.x;
    const bool vt = bid >= 512;
    const int z = vt ? 2 : (bid >> 8);
    const int t = vt ? (bid - 512) : (bid & 255);
    const int n0 = vt ? (t & 31) * 128 : (t & 7) * 128;
    const int m0 = vt ? (t >> 5) * 128 : (t >> 3) * 128;
    const u16* Ap = vt ? (Wt + 2 * WSZ) : xb;
    const u16* Bp = vt ? xb : (Wt + (size_t)z * WSZ);
    const float* bias = vt ? bv : (z ? bk : bq);

    frag_cd acc[4][4];
    #pragma unroll
    for (int i = 0; i < 4; i++)
        #pragma unroll
        for (int j = 0; j < 4; j++) acc[i][j] = (frag_cd){0.f, 0.f, 0.f, 0.f};

    const int wm = (w >> 1) * 64, wn = (w & 1) * 64;

    for (int k0 = 0; k0 < D_MODEL; k0 += BK) {
        __syncthreads();
        #pragma unroll
        for (int it = 0; it < 4; ++it) {
            int c = it * 256 + tid;
            int r = c >> 3, c8 = c & 7;
            const u16* ga = Ap + (size_t)(m0 + r) * D_MODEL + k0 + c8 * 8;
            char* la = (char*)As + (it * 256 + w * 64) * 16;
            __builtin_amdgcn_global_load_lds((const __attribute__((address_space(1))) void*)ga,
                                             (__attribute__((address_space(3))) void*)la, 16, 0, 0);
            const u16* gb = Bp + (size_t)(n0 + r) * D_MODEL + k0 + c8 * 8;
            char* lb = (char*)Bs + (it * 256 + w * 64) * 16;
            __builtin_amdgcn_global_load_lds((const __attribute__((address_space(1))) void*)gb,
                                             (__attribute__((address_space(3))) void*)lb, 16, 0, 0);
        }
        __syncthreads();

        #pragma unroll
        for (int kc = 0; kc < 2; ++kc) {
            frag_ab av[4], bvv[4];
            #pragma unroll
            for (int i = 0; i < 4; i++)
                av[i] = *(const frag_ab*)&As[(wm + i * 16 + lrow) * BK + kc * 32 + lquad * 8];
            #pragma unroll
            for (int j = 0; j < 4; j++)
                bvv[j] = *(const frag_ab*)&Bs[(wn + j * 16 + lrow) * BK + kc * 32 + lquad * 8];
            #pragma unroll
            for (int i = 0; i < 4; i++)
                #pragma unroll
                for (int j = 0; j < 4; j++)
                    acc[i][j] = __builtin_amdgcn_mfma_f32_16x16x32_bf16(av[i], bvv[j], acc[i][j], 0, 0, 0);
        }
    }

    const float scale = (!vt && z == 0) ? QSCALE : 1.0f;
    #pragma unroll
    for (int j = 0; j < 4; j++) {
        int gn = n0 + wn + j * 16 + lrow;
        #pragma unroll
        for (int i = 0; i < 4; i++) {
            #pragma unroll
            for (int rr = 0; rr < 4; ++rr) {
                int gm = m0 + wm + i * 16 + lquad * 4 + rr;
                if (!vt) {
                    float v = (acc[i][j][rr] + bias[gn]) * scale;
                    u16* oz = QKw + (size_t)z * ((size_t)MTOT * D_MODEL);
                    int b = gm >> 11, s = gm & (SEQ - 1);
                    int h = gn >> 6, d = gn & (HDIM - 1);
                    oz[(((size_t)(b * NHEAD + h)) * SEQ + s) * HDIM + d] = f2u(v);
                } else {
                    float v = acc[i][j][rr] + bias[gm];
                    int h = gm >> 6, d = gm & (HDIM - 1);
                    int b = gn >> 11, s = gn & (SEQ - 1);
                    Vtw[(((size_t)(b * NHEAD + h)) * HDIM + d) * SEQ + s] = f2u(v);
                }
            }
        }
    }
}

// ---------------------------------------------------------------------------
// Out projection: 64x128 tile (512 blocks), fp32 store.
// ---------------------------------------------------------------------------
__launch_bounds__(256, 2)
__global__ void gemm_out(const u16* __restrict__ A, const u16* __restrict__ Wt,
                         const float* __restrict__ bias, float* __restrict__ out) {
    constexpr int BK = 64;
    __shared__ __attribute__((aligned(16))) u16 As[64 * BK];
    __shared__ __attribute__((aligned(16))) u16 Bs[128 * BK];

    const int tid = threadIdx.x;
    const int w = tid >> 6;
    const int lane = tid & 63;
    const int lrow = lane & 15, lquad = lane >> 4;
    const int m0 = blockIdx.y * 64, n0 = blockIdx.x * 128;

    frag_cd acc[2][4];
    #pragma unroll
    for (int i = 0; i < 2; i++)
        #pragma unroll
        for (int j = 0; j < 4; j++) acc[i][j] = (frag_cd){0.f, 0.f, 0.f, 0.f};

    const int wm = (w >> 1) * 32, wn = (w & 1) * 64;

    for (int k0 = 0; k0 < D_MODEL; k0 += BK) {
        __syncthreads();
        #pragma unroll
        for (int it = 0; it < 2; ++it) {
            int c = it * 256 + tid;
            int r = c >> 3, c8 = c & 7;
            const u16* ga = A + (size_t)(m0 + r) * D_MODEL + k0 + c8 * 8;
            char* la = (char*)As + (it * 256 + w * 64) * 16;
            __builtin_amdgcn_global_load_lds((const __attribute__((address_space(1))) void*)ga,
                                             (__attribute__((address_space(3))) void*)la, 16, 0, 0);
        }
        #pragma unroll
        for (int it = 0; it < 4; ++it) {
            int c = it * 256 + tid;
            int r = c >> 3, c8 = c & 7;
            const u16* gb = Wt + (size_t)(n0 + r) * D_MODEL + k0 + c8 * 8;
            char* lb = (char*)Bs + (it * 256 + w * 64) * 16;
            __builtin_amdgcn_global_load_lds((const __attribute__((address_space(1))) void*)gb,
                                             (__attribute__((address_space(3))) void*)lb, 16, 0, 0);
        }
        __syncthreads();

        #pragma unroll
        for (int kc = 0; kc < 2; ++kc) {
            frag_ab av[2], bvv[4];
            #pragma unroll
            for (int i = 0; i < 2; i++)
                av[i] = *(const frag_ab*)&As[(wm + i * 16 + lrow) * BK + kc * 32 + lquad * 8];
            #pragma unroll
            for (int j = 0; j < 4; j++)
                bvv[j] = *(const frag_ab*)&Bs[(wn + j * 16 + lrow) * BK + kc * 32 + lquad * 8];
            #pragma unroll
            for (int i = 0; i < 2; i++)
                #pragma unroll
                for (int j = 0; j < 4; j++)
                    acc[i][j] = __builtin_amdgcn_mfma_f32_16x16x32_bf16(av[i], bvv[j], acc[i][j], 0, 0, 0);
        }
    }

    #pragma unroll
    for (int j = 0; j < 4; j++) {
        int gn = n0 + wn + j * 16 + lrow;
        float bvf = bias[gn];
        #pragma unroll
        for (int i = 0; i < 2; i++)
            #pragma unroll
            for (int rr = 0; rr < 4; ++rr) {
                int gm = m0 + wm + i * 16 + lquad * 4 + rr;
                out[(size_t)gm * D_MODEL + gn] = acc[i][j][rr] + bvf;
            }
    }
}

// ---------------------------------------------------------------------------
// Attention, R12: grid (32,32) = 1024 blocks (4/CU), 512 thr = 8 waves,
// 32 waves/CU target. q-tile 64: wave w -> q-group qg=w&3 (16 q), key-half
// kh=w>>2 (keys kh*64..+63 of each staged 128-key tile). Single-buffered
// 32KB LDS (K 16KB + V^T 16KB), global_load_lds staging with source-side
// XOR swizzle (identical pattern to R10, verified). Chunked compute (2x32
// keys) keeps live VGPR low. Partial O^T + rowsum combined additively via
// LDS (comb stride 68 f32 to spread banks); waves kh=0 store O.
// ---------------------------------------------------------------------------
__launch_bounds__(512, 8)
__global__ void attn_kernel(const u16* __restrict__ Q, const u16* __restrict__ K,
                            const u16* __restrict__ Vt, u16* __restrict__ O) {
    __shared__ __attribute__((aligned(16))) u16 SMEM[16384];  // 32 KB
    u16* Ks = SMEM;            // [128 keys][64 d], source-swizzled chunks
    u16* Vs = SMEM + 8192;     // [64 d][128 keys], source-swizzled chunks

    const int tid = threadIdx.x;
    const int w = tid >> 6;           // 8 waves
    const int lane = tid & 63;
    const int lrow = lane & 15, lquad = lane >> 4;
    const int qg = w & 3;             // q-group (16 q)
    const int kh = w >> 2;            // key half: 0 -> keys [0,64), 1 -> [64,128)
    const int bh = blockIdx.y;
    const int q0 = blockIdx.x * 64;
    const size_t base = (size_t)bh * SEQ * HDIM;
    const u16* Qg = Q + base;
    const u16* Kg = K + base;
    const u16* Vg = Vt + base;  // [d][s]

    // Q as B-operand of 16x16x32: lane holds q = lrow, d = kc*32 + lquad*8 + j
    frag_ab qf[2];
    #pragma unroll
    for (int kc = 0; kc < 2; ++kc)
        qf[kc] = *(const frag_ab*)&Qg[(size_t)(q0 + qg * 16 + lrow) * HDIM + kc * 32 + lquad * 8];

    frag_cd accOT[4];   // partial O^T: lane q = lrow, d = df*16 + lquad*4 + i
    #pragma unroll
    for (int df = 0; df < 4; df++) accOT[df] = (frag_cd){0.f, 0.f, 0.f, 0.f};
    f32x2 lacc2 = (f32x2){0.f, 0.f};  // packed rowsum partial

    for (int kt = 0; kt < SEQ / 128; ++kt) {
        __syncthreads();   // all reads of SMEM done
        {   // stage 128-key K/V tile: pre-swizzled global source, linear LDS dest
            const u16* Kt = Kg + (size_t)(kt * 128) * HDIM;
            #pragma unroll
            for (int it = 0; it < 2; ++it) {
                const int c = it * 512 + tid;
                // K: row rk (128), 16B chunk ck of 8; source chunk = ck ^ (rk&7)
                const int rk = c >> 3, ck = c & 7;
                const u16* gk = Kt + rk * HDIM + ((ck ^ (rk & 7)) << 3);
                char* lk = (char*)Ks + (it * 512 + w * 64) * 16;
                __builtin_amdgcn_global_load_lds((const __attribute__((address_space(1))) void*)gk,
                                                 (__attribute__((address_space(3))) void*)lk, 16, 0, 0);
                // V^T: row d=rv (64), 16B chunk gv of 16; source chunk = gv ^ (rv&7)
                const int rv = c >> 4, gv = c & 15;
                const u16* gvp = Vg + (size_t)rv * SEQ + kt * 128 + ((gv ^ (rv & 7)) << 3);
                char* lv = (char*)Vs + (it * 512 + w * 64) * 16;
                __builtin_amdgcn_global_load_lds((const __attribute__((address_space(1))) void*)gvp,
                                                 (__attribute__((address_space(3))) void*)lv, 16, 0, 0);
            }
        }
        __syncthreads();   // drain vmcnt, tile visible

        // this wave's 64 keys, in 2 chunks of 32 to cap live registers
        #pragma unroll
        for (int ch = 0; ch < 2; ++ch) {
            frag_cd sc[2];
            #pragma unroll
            for (int m = 0; m < 2; m++) sc[m] = (frag_cd){0.f, 0.f, 0.f, 0.f};
            #pragma unroll
            for (int kc = 0; kc < 2; ++kc) {
                const int cswz = (((kc << 2) + lquad) ^ (lrow & 7)) << 3;  // swizzled d-chunk (u16)
                #pragma unroll
                for (int m = 0; m < 2; m++) {
                    const int row = kh * 64 + (ch * 2 + m) * 16 + lrow;
                    frag_ab kf = *(const frag_ab*)&Ks[row * 64 + cswz];
                    sc[m] = __builtin_amdgcn_mfma_f32_16x16x32_bf16(kf, qf[kc], sc[m], 0, 0, 0);
                }
            }

            frag_s4 pk[2];
            #pragma unroll
            for (int m = 0; m < 2; m++) {
                float e0 = exp2f(sc[m][0]), e1 = exp2f(sc[m][1]);
                float e2 = exp2f(sc[m][2]), e3 = exp2f(sc[m][3]);
                f32x2 a = {e0, e1}, b2 = {e2, e3};
                lacc2 += a + b2;  // v_pk_add_f32
                union { frag_s4 s; unsigned int u[2]; } pu;
                pu.u[0] = pkrn(e0, e1);
                pu.u[1] = pkrn(e2, e3);
                pk[m] = pu.s;
            }

            // O^T += V^T . P^T : A = V^T (m=d, k=this wave's keys, swizzled b64)
            #pragma unroll
            for (int m = 0; m < 2; m++) {
                const int gc = ((kh * 4 + ch * 2 + m) << 1) + (lquad >> 1);
                #pragma unroll
                for (int df = 0; df < 4; df++) {
                    const int dr = df * 16 + lrow;
                    frag_s4 vf = *(const frag_s4*)&Vs[dr * 128 + ((gc ^ (lrow & 7)) << 3) + (lquad & 1) * 4];
                    accOT[df] = __builtin_amdgcn_mfma_f32_16x16x16bf16_1k(vf, pk[m], accOT[df], 0, 0, 0);
                }
            }
        }
    }

    // rowsum: pack-halves + quad reduce (lanes lrow, +16, +32, +48 hold same q)
    float lacc = lacc2[0] + lacc2[1];
    lacc += __shfl_xor(lacc, 16);
    lacc += __shfl_xor(lacc, 32);

    // combine key-halves additively via LDS (reuse SMEM; stride 68 spreads banks)
    float* comb = (float*)SMEM;              // [64 q][68], 17408 B
    float* lsum = (float*)SMEM + 64 * 68;    // 64 f32
    __syncthreads();   // all tile reads done before overwrite
    if (kh) {
        float* crow = comb + (qg * 16 + lrow) * 68;
        #pragma unroll
        for (int df = 0; df < 4; df++)
            *(float4*)&crow[df * 16 + lquad * 4] =
                (float4){accOT[df][0], accOT[df][1], accOT[df][2], accOT[df][3]};
        if (lquad == 0) lsum[qg * 16 + lrow] = lacc;
    }
    __syncthreads();
    if (!kh) {
        const float* crow = comb + (qg * 16 + lrow) * 68;
        #pragma unroll
        for (int df = 0; df < 4; df++) {
            float4 c = *(const float4*)&crow[df * 16 + lquad * 4];
            accOT[df][0] += c.x; accOT[df][1] += c.y;
            accOT[df][2] += c.z; accOT[df][3] += c.w;
        }
        lacc += lsum[qg * 16 + lrow];

        // epilogue: lane owns one q -> single reciprocal; b64 stores (packed cvt)
        const int b = bh >> 4, h = bh & (NHEAD - 1);
        const int s = q0 + qg * 16 + lrow;
        const float inv = 1.0f / lacc;
        u16* orow = O + ((size_t)(b * SEQ + s)) * D_MODEL + h * HDIM;
        #pragma unroll
        for (int df = 0; df < 4; df++) {
            union { unsigned int u[2]; ushort4 s4; } o;
            o.u[0] = pkrn(accOT[df][0] * inv, accOT[df][1] * inv);
            o.u[1] = pkrn(accOT[df][2] * inv, accOT[df][3] * inv);
            *(ushort4*)&orow[df * 16 + lquad * 4] = o.s4;
        }
    }
}

// ---------------------------------------------------------------------------
// Workspace (u16 elems): xb [0,4M) | Wt 4 slabs [4M,8M) | Q,K [8M,16M)
//                        Vt [16M,20M) | attn-out [20M,24M)   = 48 MB
// ---------------------------------------------------------------------------
extern "C" void kernel_launch(void* const* d_in, const int* in_sizes, int n_in,
                              void* d_out, int out_size, void* d_ws, size_t ws_size,
                              hipStream_t stream) {
    const float* x  = (const float*)d_in[0];
    const float* Wq = (const float*)d_in[1];
    const float* bq = (const float*)d_in[2];
    const float* Wk = (const float*)d_in[3];
    const float* bk = (const float*)d_in[4];
    const float* Wv = (const float*)d_in[5];
    const float* bv = (const float*)d_in[6];
    const float* Wo = (const float*)d_in[7];
    const float* bo = (const float*)d_in[8];

    u16* ws = (u16*)d_ws;
    const size_t WSZ = (size_t)D_MODEL * D_MODEL;    // 1M elems
    const size_t TSZ = (size_t)MTOT * D_MODEL;       // 4M elems
    u16* xb  = ws;
    u16* Wt  = ws + 4 * WSZ;
    u16* QKw = ws + 8 * WSZ;        // Q slab 0, K slab 1
    u16* Vtw = QKw + 2 * TSZ;
    u16* Aw  = Vtw + TSZ;

    prep<<<dim3(32, 32, 5), dim3(32, 8), 0, stream>>>(Wq, Wk, Wv, Wo, x, Wt, xb);
    gemm_qkvt<<<dim3(768), 256, 0, stream>>>(xb, Wt, bq, bk, bv, QKw, Vtw);
    attn_kernel<<<dim3(32, 32), 512, 0, stream>>>(QKw, QKw + TSZ, Vtw, Aw);
    gemm_out<<<dim3(8, 64), 256, 0, stream>>>(Aw, Wt + 3 * WSZ, bo, (float*)d_out);
}

// Round 4
// 213.177 us; speedup vs baseline: 1.0903x; 1.0459x over previous
//
#include <hip/hip_runtime.h>
#include <hip/hip_bf16.h>

// MultiBertAttention fp32 I/O, bf16 MFMA internals.
// R13: attn VALU surgery. R12 showed VALU=60% is the dominant pipe (MFMA 29%,
//      HBM 13%); the biggest removable VALU block is libm exp2f's ~5-instr
//      denormal/range expansion around v_exp_f32. Scores are bounded (|s|<~30)
//      so raw v_exp_f32 is exact -> fexp2() builtin/asm. Also hoisted ALL
//      staging addresses (global src ptrs advanced by constant stride; LDS
//      dests fixed) and LDS fragment base pointers out of the K-loop.
//      Grid/layouts/swizzles identical to R12 (verified).
//      prep / gemm_qkvt / gemm_out unchanged.

typedef unsigned short u16;

#define D_MODEL 1024
#define NHEAD 16
#define HDIM 64
#define BATCH 2
#define SEQ 2048
#define MTOT (BATCH * SEQ)  // 4096

#define QSCALE 0.18033688011112042f  // (1/8) * log2(e)

using frag_ab = __attribute__((ext_vector_type(8))) short;  // 8 bf16 (16x16x32 A/B)
using frag_s4 = __attribute__((ext_vector_type(4))) short;  // 4 bf16 (16x16x16 A/B)
using frag_cd = __attribute__((ext_vector_type(4))) float;  // 4 fp32
using f32x2   = __attribute__((ext_vector_type(2))) float;

__device__ __forceinline__ u16 f2u(float f) {  // RNE fp32->bf16
    union { float f; unsigned int i; } x;
    x.f = f;
    unsigned int r = x.i + 0x7fffu + ((x.i >> 16) & 1u);
    return (u16)(r >> 16);
}
__device__ __forceinline__ unsigned int pkrn(float a, float b) {  // v_cvt_pk_bf16_f32
    union { __hip_bfloat162 h; unsigned int u; } c;
    c.h = __float22bfloat162_rn(float2{a, b});
    return c.u;
}
__device__ __forceinline__ float fexp2(float x) {  // raw v_exp_f32 (inputs bounded)
#if __has_builtin(__builtin_amdgcn_exp2f)
    return __builtin_amdgcn_exp2f(x);
#else
    float r;
    asm("v_exp_f32 %0, %1" : "=v"(r) : "v"(x));
    return r;
#endif
}

// ---------------------------------------------------------------------------
// prep: z<4 -> Wt[z][n][k] = bf16(W_z[k][n]); z==4 -> xb = bf16(x).
// ---------------------------------------------------------------------------
__global__ void prep(const float* __restrict__ W0, const float* __restrict__ W1,
                     const float* __restrict__ W2, const float* __restrict__ W3,
                     const float* __restrict__ X, u16* __restrict__ Wt,
                     u16* __restrict__ Xb) {
    const int z = blockIdx.z;
    const int tx = threadIdx.x, ty = threadIdx.y;
    if (z < 4) {
        __shared__ u16 t[32][33];
        const float* W = (z == 0) ? W0 : (z == 1) ? W1 : (z == 2) ? W2 : W3;
        u16* o = Wt + (size_t)z * D_MODEL * D_MODEL;
        int n0 = blockIdx.x * 32, k0 = blockIdx.y * 32;
        #pragma unroll
        for (int i = ty; i < 32; i += 8) t[i][tx] = f2u(W[(size_t)(k0 + i) * D_MODEL + n0 + tx]);
        __syncthreads();
        #pragma unroll
        for (int i = ty; i < 32; i += 8) o[(size_t)(n0 + i) * D_MODEL + k0 + tx] = t[tx][i];
    } else {
        int tid = ty * 32 + tx;
        size_t base = ((size_t)(blockIdx.y * 32 + blockIdx.x) * 256 + tid) * 16;
        #pragma unroll
        for (int c = 0; c < 4; ++c) {
            float4 v = *(const float4*)&X[base + c * 4];
            ushort4 o;
            o.x = f2u(v.x); o.y = f2u(v.y); o.z = f2u(v.z); o.w = f2u(v.w);
            *(ushort4*)&Xb[base + c * 4] = o;
        }
    }
}

// ---------------------------------------------------------------------------
// Fused QKV + V^T GEMM, 768 blocks (1D). 128x128 tile, BK=64, global_load_lds.
// ---------------------------------------------------------------------------
__launch_bounds__(256, 3)
__global__ void gemm_qkvt(const u16* __restrict__ xb, const u16* __restrict__ Wt,
                          const float* __restrict__ bq, const float* __restrict__ bk,
                          const float* __restrict__ bv, u16* __restrict__ QKw,
                          u16* __restrict__ Vtw) {
    constexpr int BK = 64;
    __shared__ __attribute__((aligned(16))) u16 As[128 * BK];
    __shared__ __attribute__((aligned(16))) u16 Bs[128 * BK];

    const int tid = threadIdx.x;
    const int w = tid >> 6;
    const int lane = tid & 63;
    const int lrow = lane & 15, lquad = lane >> 4;
    const size_t WSZ = (size_t)D_MODEL * D_MODEL;

    const int bid = blockIdx.x;
    const bool vt = bid >= 512;
    const int z = vt ? 2 : (bid >> 8);
    const int t = vt ? (bid - 512) : (bid & 255);
    const int n0 = vt ? (t & 31) * 128 : (t & 7) * 128;
    const int m0 = vt ? (t >> 5) * 128 : (t >> 3) * 128;
    const u16* Ap = vt ? (Wt + 2 * WSZ) : xb;
    const u16* Bp = vt ? xb : (Wt + (size_t)z * WSZ);
    const float* bias = vt ? bv : (z ? bk : bq);

    frag_cd acc[4][4];
    #pragma unroll
    for (int i = 0; i < 4; i++)
        #pragma unroll
        for (int j = 0; j < 4; j++) acc[i][j] = (frag_cd){0.f, 0.f, 0.f, 0.f};

    const int wm = (w >> 1) * 64, wn = (w & 1) * 64;

    for (int k0 = 0; k0 < D_MODEL; k0 += BK) {
        __syncthreads();
        #pragma unroll
        for (int it = 0; it < 4; ++it) {
            int c = it * 256 + tid;
            int r = c >> 3, c8 = c & 7;
            const u16* ga = Ap + (size_t)(m0 + r) * D_MODEL + k0 + c8 * 8;
            char* la = (char*)As + (it * 256 + w * 64) * 16;
            __builtin_amdgcn_global_load_lds((const __attribute__((address_space(1))) void*)ga,
                                             (__attribute__((address_space(3))) void*)la, 16, 0, 0);
            const u16* gb = Bp + (size_t)(n0 + r) * D_MODEL + k0 + c8 * 8;
            char* lb = (char*)Bs + (it * 256 + w * 64) * 16;
            __builtin_amdgcn_global_load_lds((const __attribute__((address_space(1))) void*)gb,
                                             (__attribute__((address_space(3))) void*)lb, 16, 0, 0);
        }
        __syncthreads();

        #pragma unroll
        for (int kc = 0; kc < 2; ++kc) {
            frag_ab av[4], bvv[4];
            #pragma unroll
            for (int i = 0; i < 4; i++)
                av[i] = *(const frag_ab*)&As[(wm + i * 16 + lrow) * BK + kc * 32 + lquad * 8];
            #pragma unroll
            for (int j = 0; j < 4; j++)
                bvv[j] = *(const frag_ab*)&Bs[(wn + j * 16 + lrow) * BK + kc * 32 + lquad * 8];
            #pragma unroll
            for (int i = 0; i < 4; i++)
                #pragma unroll
                for (int j = 0; j < 4; j++)
                    acc[i][j] = __builtin_amdgcn_mfma_f32_16x16x32_bf16(av[i], bvv[j], acc[i][j], 0, 0, 0);
        }
    }

    const float scale = (!vt && z == 0) ? QSCALE : 1.0f;
    #pragma unroll
    for (int j = 0; j < 4; j++) {
        int gn = n0 + wn + j * 16 + lrow;
        #pragma unroll
        for (int i = 0; i < 4; i++) {
            #pragma unroll
            for (int rr = 0; rr < 4; ++rr) {
                int gm = m0 + wm + i * 16 + lquad * 4 + rr;
                if (!vt) {
                    float v = (acc[i][j][rr] + bias[gn]) * scale;
                    u16* oz = QKw + (size_t)z * ((size_t)MTOT * D_MODEL);
                    int b = gm >> 11, s = gm & (SEQ - 1);
                    int h = gn >> 6, d = gn & (HDIM - 1);
                    oz[(((size_t)(b * NHEAD + h)) * SEQ + s) * HDIM + d] = f2u(v);
                } else {
                    float v = acc[i][j][rr] + bias[gm];
                    int h = gm >> 6, d = gm & (HDIM - 1);
                    int b = gn >> 11, s = gn & (SEQ - 1);
                    Vtw[(((size_t)(b * NHEAD + h)) * HDIM + d) * SEQ + s] = f2u(v);
                }
            }
        }
    }
}

// ---------------------------------------------------------------------------
// Out projection: 64x128 tile (512 blocks), fp32 store.
// ---------------------------------------------------------------------------
__launch_bounds__(256, 2)
__global__ void gemm_out(const u16* __restrict__ A, const u16* __restrict__ Wt,
                         const float* __restrict__ bias, float* __restrict__ out) {
    constexpr int BK = 64;
    __shared__ __attribute__((aligned(16))) u16 As[64 * BK];
    __shared__ __attribute__((aligned(16))) u16 Bs[128 * BK];

    const int tid = threadIdx.x;
    const int w = tid >> 6;
    const int lane = tid & 63;
    const int lrow = lane & 15, lquad = lane >> 4;
    const int m0 = blockIdx.y * 64, n0 = blockIdx.x * 128;

    frag_cd acc[2][4];
    #pragma unroll
    for (int i = 0; i < 2; i++)
        #pragma unroll
        for (int j = 0; j < 4; j++) acc[i][j] = (frag_cd){0.f, 0.f, 0.f, 0.f};

    const int wm = (w >> 1) * 32, wn = (w & 1) * 64;

    for (int k0 = 0; k0 < D_MODEL; k0 += BK) {
        __syncthreads();
        #pragma unroll
        for (int it = 0; it < 2; ++it) {
            int c = it * 256 + tid;
            int r = c >> 3, c8 = c & 7;
            const u16* ga = A + (size_t)(m0 + r) * D_MODEL + k0 + c8 * 8;
            char* la = (char*)As + (it * 256 + w * 64) * 16;
            __builtin_amdgcn_global_load_lds((const __attribute__((address_space(1))) void*)ga,
                                             (__attribute__((address_space(3))) void*)la, 16, 0, 0);
        }
        #pragma unroll
        for (int it = 0; it < 4; ++it) {
            int c = it * 256 + tid;
            int r = c >> 3, c8 = c & 7;
            const u16* gb = Wt + (size_t)(n0 + r) * D_MODEL + k0 + c8 * 8;
            char* lb = (char*)Bs + (it * 256 + w * 64) * 16;
            __builtin_amdgcn_global_load_lds((const __attribute__((address_space(1))) void*)gb,
                                             (__attribute__((address_space(3))) void*)lb, 16, 0, 0);
        }
        __syncthreads();

        #pragma unroll
        for (int kc = 0; kc < 2; ++kc) {
            frag_ab av[2], bvv[4];
            #pragma unroll
            for (int i = 0; i < 2; i++)
                av[i] = *(const frag_ab*)&As[(wm + i * 16 + lrow) * BK + kc * 32 + lquad * 8];
            #pragma unroll
            for (int j = 0; j < 4; j++)
                bvv[j] = *(const frag_ab*)&Bs[(wn + j * 16 + lrow) * BK + kc * 32 + lquad * 8];
            #pragma unroll
            for (int i = 0; i < 2; i++)
                #pragma unroll
                for (int j = 0; j < 4; j++)
                    acc[i][j] = __builtin_amdgcn_mfma_f32_16x16x32_bf16(av[i], bvv[j], acc[i][j], 0, 0, 0);
        }
    }

    #pragma unroll
    for (int j = 0; j < 4; j++) {
        int gn = n0 + wn + j * 16 + lrow;
        float bvf = bias[gn];
        #pragma unroll
        for (int i = 0; i < 2; i++)
            #pragma unroll
            for (int rr = 0; rr < 4; ++rr) {
                int gm = m0 + wm + i * 16 + lquad * 4 + rr;
                out[(size_t)gm * D_MODEL + gn] = acc[i][j][rr] + bvf;
            }
    }
}

// ---------------------------------------------------------------------------
// Attention, R13 (= R12 structure + VALU surgery). Grid (32,32), 512 thr,
// 8 waves: wave w -> q-group qg=w&3 (16 q), key-half kh=w>>2. Single-buffered
// 32KB LDS, global_load_lds staging with source-side XOR swizzle. Partial
// O^T + rowsum combined additively via LDS. All global staging pointers and
// LDS fragment pointers hoisted out of the K-loop; exp via raw v_exp_f32.
// ---------------------------------------------------------------------------
__launch_bounds__(512, 8)
__global__ void attn_kernel(const u16* __restrict__ Q, const u16* __restrict__ K,
                            const u16* __restrict__ Vt, u16* __restrict__ O) {
    __shared__ __attribute__((aligned(16))) u16 SMEM[16384];  // 32 KB
    u16* Ks = SMEM;            // [128 keys][64 d], source-swizzled chunks
    u16* Vs = SMEM + 8192;     // [64 d][128 keys], source-swizzled chunks

    const int tid = threadIdx.x;
    const int w = tid >> 6;           // 8 waves
    const int lane = tid & 63;
    const int lrow = lane & 15, lquad = lane >> 4;
    const int qg = w & 3;             // q-group (16 q)
    const int kh = w >> 2;            // key half: 0 -> keys [0,64), 1 -> [64,128)
    const int bh = blockIdx.y;
    const int q0 = blockIdx.x * 64;
    const size_t base = (size_t)bh * SEQ * HDIM;
    const u16* Qg = Q + base;
    const u16* Kg = K + base;
    const u16* Vg = Vt + base;  // [d][s]

    // Q as B-operand of 16x16x32: lane holds q = lrow, d = kc*32 + lquad*8 + j
    frag_ab qf[2];
    #pragma unroll
    for (int kc = 0; kc < 2; ++kc)
        qf[kc] = *(const frag_ab*)&Qg[(size_t)(q0 + qg * 16 + lrow) * HDIM + kc * 32 + lquad * 8];

    frag_cd accOT[4];   // partial O^T: lane q = lrow, d = df*16 + lquad*4 + i
    #pragma unroll
    for (int df = 0; df < 4; df++) accOT[df] = (frag_cd){0.f, 0.f, 0.f, 0.f};
    f32x2 lacc2 = (f32x2){0.f, 0.f};  // packed rowsum partial

    // ---- hoisted staging addresses (kt-invariant except constant stride) ----
    // K: chunk c of 1024 -> row rk=c>>3 (128), chunk ck=c&7; src chunk = ck^(rk&7)
    // V: chunk c of 1024 -> row rv=c>>4 (64), chunk gv=c&15; src chunk = gv^(rv&7)
    const int c0 = tid, c1 = 512 + tid;
    const u16* gk0 = Kg + ((c0 >> 3) * HDIM + (((c0 & 7) ^ ((c0 >> 3) & 7)) << 3));
    const u16* gk1 = Kg + ((c1 >> 3) * HDIM + (((c1 & 7) ^ ((c1 >> 3) & 7)) << 3));
    const u16* gv0 = Vg + ((size_t)(c0 >> 4) * SEQ + (((c0 & 15) ^ ((c0 >> 4) & 7)) << 3));
    const u16* gv1 = Vg + ((size_t)(c1 >> 4) * SEQ + (((c1 & 15) ^ ((c1 >> 4) & 7)) << 3));
    char* lk0 = (char*)Ks + (0 * 512 + w * 64) * 16;   // + implicit lane*16
    char* lk1 = (char*)Ks + (1 * 512 + w * 64) * 16;
    char* lv0 = (char*)Vs + (0 * 512 + w * 64) * 16;
    char* lv1 = (char*)Vs + (1 * 512 + w * 64) * 16;

    // ---- hoisted LDS fragment base pointers (kt-invariant) ----
    const u16* kb0 = Ks + (kh * 64 + lrow) * 64 + (((0 + lquad) ^ (lrow & 7)) << 3);
    const u16* kb1 = Ks + (kh * 64 + lrow) * 64 + (((4 + lquad) ^ (lrow & 7)) << 3);
    const u16* vb[4];
    #pragma unroll
    for (int cm = 0; cm < 4; ++cm) {
        const int gc = ((kh * 4 + cm) << 1) + (lquad >> 1);
        vb[cm] = Vs + lrow * 128 + ((gc ^ (lrow & 7)) << 3) + (lquad & 1) * 4;
    }

    for (int kt = 0; kt < SEQ / 128; ++kt) {
        __syncthreads();   // all reads of SMEM done
        __builtin_amdgcn_global_load_lds((const __attribute__((address_space(1))) void*)gk0,
                                         (__attribute__((address_space(3))) void*)lk0, 16, 0, 0);
        __builtin_amdgcn_global_load_lds((const __attribute__((address_space(1))) void*)gk1,
                                         (__attribute__((address_space(3))) void*)lk1, 16, 0, 0);
        __builtin_amdgcn_global_load_lds((const __attribute__((address_space(1))) void*)gv0,
                                         (__attribute__((address_space(3))) void*)lv0, 16, 0, 0);
        __builtin_amdgcn_global_load_lds((const __attribute__((address_space(1))) void*)gv1,
                                         (__attribute__((address_space(3))) void*)lv1, 16, 0, 0);
        gk0 += 128 * HDIM; gk1 += 128 * HDIM;   // next 128-key tile
        gv0 += 128;        gv1 += 128;
        __syncthreads();   // drain vmcnt, tile visible

        // this wave's 64 keys, in 2 chunks of 32 to cap live registers
        #pragma unroll
        for (int ch = 0; ch < 2; ++ch) {
            frag_cd sc[2];
            #pragma unroll
            for (int m = 0; m < 2; m++) sc[m] = (frag_cd){0.f, 0.f, 0.f, 0.f};
            #pragma unroll
            for (int m = 0; m < 2; m++) {
                frag_ab kf0 = *(const frag_ab*)(kb0 + (ch * 2 + m) * 1024);
                sc[m] = __builtin_amdgcn_mfma_f32_16x16x32_bf16(kf0, qf[0], sc[m], 0, 0, 0);
                frag_ab kf1 = *(const frag_ab*)(kb1 + (ch * 2 + m) * 1024);
                sc[m] = __builtin_amdgcn_mfma_f32_16x16x32_bf16(kf1, qf[1], sc[m], 0, 0, 0);
            }

            frag_s4 pk[2];
            #pragma unroll
            for (int m = 0; m < 2; m++) {
                float e0 = fexp2(sc[m][0]), e1 = fexp2(sc[m][1]);
                float e2 = fexp2(sc[m][2]), e3 = fexp2(sc[m][3]);
                f32x2 a = {e0, e1}, b2 = {e2, e3};
                lacc2 += a + b2;  // v_pk_add_f32
                union { frag_s4 s; unsigned int u[2]; } pu;
                pu.u[0] = pkrn(e0, e1);
                pu.u[1] = pkrn(e2, e3);
                pk[m] = pu.s;
            }

            // O^T += V^T . P^T : A = V^T (m=d, k=this wave's keys, swizzled b64)
            #pragma unroll
            for (int m = 0; m < 2; m++) {
                const u16* vp = vb[ch * 2 + m];
                #pragma unroll
                for (int df = 0; df < 4; df++) {
                    frag_s4 vf = *(const frag_s4*)(vp + df * 2048);
                    accOT[df] = __builtin_amdgcn_mfma_f32_16x16x16bf16_1k(vf, pk[m], accOT[df], 0, 0, 0);
                }
            }
        }
    }

    // rowsum: pack-halves + quad reduce (lanes lrow, +16, +32, +48 hold same q)
    float lacc = lacc2[0] + lacc2[1];
    lacc += __shfl_xor(lacc, 16);
    lacc += __shfl_xor(lacc, 32);

    // combine key-halves additively via LDS (reuse SMEM; stride 68 spreads banks)
    float* comb = (float*)SMEM;              // [64 q][68], 17408 B
    float* lsum = (float*)SMEM + 64 * 68;    // 64 f32
    __syncthreads();   // all tile reads done before overwrite
    if (kh) {
        float* crow = comb + (qg * 16 + lrow) * 68;
        #pragma unroll
        for (int df = 0; df < 4; df++)
            *(float4*)&crow[df * 16 + lquad * 4] =
                (float4){accOT[df][0], accOT[df][1], accOT[df][2], accOT[df][3]};
        if (lquad == 0) lsum[qg * 16 + lrow] = lacc;
    }
    __syncthreads();
    if (!kh) {
        const float* crow = comb + (qg * 16 + lrow) * 68;
        #pragma unroll
        for (int df = 0; df < 4; df++) {
            float4 c = *(const float4*)&crow[df * 16 + lquad * 4];
            accOT[df][0] += c.x; accOT[df][1] += c.y;
            accOT[df][2] += c.z; accOT[df][3] += c.w;
        }
        lacc += lsum[qg * 16 + lrow];

        // epilogue: lane owns one q -> single reciprocal; b64 stores (packed cvt)
        const int b = bh >> 4, h = bh & (NHEAD - 1);
        const int s = q0 + qg * 16 + lrow;
        const float inv = 1.0f / lacc;
        u16* orow = O + ((size_t)(b * SEQ + s)) * D_MODEL + h * HDIM;
        #pragma unroll
        for (int df = 0; df < 4; df++) {
            union { unsigned int u[2]; ushort4 s4; } o;
            o.u[0] = pkrn(accOT[df][0] * inv, accOT[df][1] * inv);
            o.u[1] = pkrn(accOT[df][2] * inv, accOT[df][3] * inv);
            *(ushort4*)&orow[df * 16 + lquad * 4] = o.s4;
        }
    }
}

// ---------------------------------------------------------------------------
// Workspace (u16 elems): xb [0,4M) | Wt 4 slabs [4M,8M) | Q,K [8M,16M)
//                        Vt [16M,20M) | attn-out [20M,24M)   = 48 MB
// ---------------------------------------------------------------------------
extern "C" void kernel_launch(void* const* d_in, const int* in_sizes, int n_in,
                              void* d_out, int out_size, void* d_ws, size_t ws_size,
                              hipStream_t stream) {
    const float* x  = (const float*)d_in[0];
    const float* Wq = (const float*)d_in[1];
    const float* bq = (const float*)d_in[2];
    const float* Wk = (const float*)d_in[3];
    const float* bk = (const float*)d_in[4];
    const float* Wv = (const float*)d_in[5];
    const float* bv = (const float*)d_in[6];
    const float* Wo = (const float*)d_in[7];
    const float* bo = (const float*)d_in[8];

    u16* ws = (u16*)d_ws;
    const size_t WSZ = (size_t)D_MODEL * D_MODEL;    // 1M elems
    const size_t TSZ = (size_t)MTOT * D_MODEL;       // 4M elems
    u16* xb  = ws;
    u16* Wt  = ws + 4 * WSZ;
    u16* QKw = ws + 8 * WSZ;        // Q slab 0, K slab 1
    u16* Vtw = QKw + 2 * TSZ;
    u16* Aw  = Vtw + TSZ;

    prep<<<dim3(32, 32, 5), dim3(32, 8), 0, stream>>>(Wq, Wk, Wv, Wo, x, Wt, xb);
    gemm_qkvt<<<dim3(768), 256, 0, stream>>>(xb, Wt, bq, bk, bv, QKw, Vtw);
    attn_kernel<<<dim3(32, 32), 512, 0, stream>>>(QKw, QKw + TSZ, Vtw, Aw);
    gemm_out<<<dim3(8, 64), 256, 0, stream>>>(Aw, Wt + 3 * WSZ, bo, (float*)d_out);
}

// Round 5
// 210.989 us; speedup vs baseline: 1.1016x; 1.0104x over previous
//
#include <hip/hip_runtime.h>
#include <hip/hip_bf16.h>

// MultiBertAttention fp32 I/O, bf16 MFMA internals.
// R14: L2-locality round. All three heavy kernels get XCD-aware bijective
//      block swizzles (dispatch round-robins consecutive blocks across 8 XCDs;
//      consecutive blocks share operand panels -> panels were replicated into
//      all 8 L2s and served from L3/HBM):
//        - gemm_qkvt: bid=(b&7)*96+(b>>3): each XCD owns 12 m-panels x 8 n of
//          one slab (~3MB working set, fits 4MB L2).
//        - gemm_out:  L=(L&7)*64+(L>>3): each XCD owns 8 m-tiles x full Wo slab.
//        - attn: each XCD owns 4 bh (2MB K/V resident in L2).
//      prep: transpose write phase vectorized (1 ushort4 store/thread).
//      attn: s_setprio(1) around MFMA clusters (T5, attn-proven).
//      Everything else identical to R13 (verified).

typedef unsigned short u16;

#define D_MODEL 1024
#define NHEAD 16
#define HDIM 64
#define BATCH 2
#define SEQ 2048
#define MTOT (BATCH * SEQ)  // 4096

#define QSCALE 0.18033688011112042f  // (1/8) * log2(e)

using frag_ab = __attribute__((ext_vector_type(8))) short;  // 8 bf16 (16x16x32 A/B)
using frag_s4 = __attribute__((ext_vector_type(4))) short;  // 4 bf16 (16x16x16 A/B)
using frag_cd = __attribute__((ext_vector_type(4))) float;  // 4 fp32
using f32x2   = __attribute__((ext_vector_type(2))) float;

__device__ __forceinline__ u16 f2u(float f) {  // RNE fp32->bf16
    union { float f; unsigned int i; } x;
    x.f = f;
    unsigned int r = x.i + 0x7fffu + ((x.i >> 16) & 1u);
    return (u16)(r >> 16);
}
__device__ __forceinline__ unsigned int pkrn(float a, float b) {  // v_cvt_pk_bf16_f32
    union { __hip_bfloat162 h; unsigned int u; } c;
    c.h = __float22bfloat162_rn(float2{a, b});
    return c.u;
}
__device__ __forceinline__ float fexp2(float x) {  // raw v_exp_f32 (inputs bounded)
#if __has_builtin(__builtin_amdgcn_exp2f)
    return __builtin_amdgcn_exp2f(x);
#else
    float r;
    asm("v_exp_f32 %0, %1" : "=v"(r) : "v"(x));
    return r;
#endif
}

// ---------------------------------------------------------------------------
// prep: z<4 -> Wt[z][n][k] = bf16(W_z[k][n]); z==4 -> xb = bf16(x).
// Write phase: one ushort4 (4 k's) store per thread.
// ---------------------------------------------------------------------------
__global__ void prep(const float* __restrict__ W0, const float* __restrict__ W1,
                     const float* __restrict__ W2, const float* __restrict__ W3,
                     const float* __restrict__ X, u16* __restrict__ Wt,
                     u16* __restrict__ Xb) {
    const int z = blockIdx.z;
    const int tx = threadIdx.x, ty = threadIdx.y;
    const int tid = ty * 32 + tx;
    if (z < 4) {
        __shared__ u16 t[32][33];   // t[k_local][n_local]
        const float* W = (z == 0) ? W0 : (z == 1) ? W1 : (z == 2) ? W2 : W3;
        u16* o = Wt + (size_t)z * D_MODEL * D_MODEL;
        int n0 = blockIdx.x * 32, k0 = blockIdx.y * 32;
        #pragma unroll
        for (int i = ty; i < 32; i += 8) t[i][tx] = f2u(W[(size_t)(k0 + i) * D_MODEL + n0 + tx]);
        __syncthreads();
        const int r = tid >> 3, c = tid & 7;   // out row n = r, k-group = c
        ushort4 o4;
        o4.x = t[4 * c + 0][r]; o4.y = t[4 * c + 1][r];
        o4.z = t[4 * c + 2][r]; o4.w = t[4 * c + 3][r];
        *(ushort4*)&o[(size_t)(n0 + r) * D_MODEL + k0 + 4 * c] = o4;
    } else {
        size_t base = ((size_t)(blockIdx.y * 32 + blockIdx.x) * 256 + tid) * 16;
        #pragma unroll
        for (int c = 0; c < 4; ++c) {
            float4 v = *(const float4*)&X[base + c * 4];
            ushort4 o;
            o.x = f2u(v.x); o.y = f2u(v.y); o.z = f2u(v.z); o.w = f2u(v.w);
            *(ushort4*)&Xb[base + c * 4] = o;
        }
    }
}

// ---------------------------------------------------------------------------
// Fused QKV + V^T GEMM, 768 blocks (1D). 128x128 tile, BK=64, global_load_lds.
// XCD swizzle: bid=(b&7)*96+(b>>3) -> each XCD owns a contiguous 96-block run
// (12 m-panels x 8 n-tiles of one slab): A-panels + B slab stay L2-resident.
// ---------------------------------------------------------------------------
__launch_bounds__(256, 3)
__global__ void gemm_qkvt(const u16* __restrict__ xb, const u16* __restrict__ Wt,
                          const float* __restrict__ bq, const float* __restrict__ bk,
                          const float* __restrict__ bv, u16* __restrict__ QKw,
                          u16* __restrict__ Vtw) {
    constexpr int BK = 64;
    __shared__ __attribute__((aligned(16))) u16 As[128 * BK];
    __shared__ __attribute__((aligned(16))) u16 Bs[128 * BK];

    const int tid = threadIdx.x;
    const int w = tid >> 6;
    const int lane = tid & 63;
    const int lrow = lane & 15, lquad = lane >> 4;
    const size_t WSZ = (size_t)D_MODEL * D_MODEL;

    const int bid0 = blockIdx.x;
    const int bid = (bid0 & 7) * 96 + (bid0 >> 3);   // XCD-chunked, bijective on 768
    const bool vt = bid >= 512;
    const int z = vt ? 2 : (bid >> 8);
    const int t = vt ? (bid - 512) : (bid & 255);
    const int n0 = vt ? (t & 31) * 128 : (t & 7) * 128;
    const int m0 = vt ? (t >> 5) * 128 : (t >> 3) * 128;
    const u16* Ap = vt ? (Wt + 2 * WSZ) : xb;
    const u16* Bp = vt ? xb : (Wt + (size_t)z * WSZ);
    const float* bias = vt ? bv : (z ? bk : bq);

    frag_cd acc[4][4];
    #pragma unroll
    for (int i = 0; i < 4; i++)
        #pragma unroll
        for (int j = 0; j < 4; j++) acc[i][j] = (frag_cd){0.f, 0.f, 0.f, 0.f};

    const int wm = (w >> 1) * 64, wn = (w & 1) * 64;

    for (int k0 = 0; k0 < D_MODEL; k0 += BK) {
        __syncthreads();
        #pragma unroll
        for (int it = 0; it < 4; ++it) {
            int c = it * 256 + tid;
            int r = c >> 3, c8 = c & 7;
            const u16* ga = Ap + (size_t)(m0 + r) * D_MODEL + k0 + c8 * 8;
            char* la = (char*)As + (it * 256 + w * 64) * 16;
            __builtin_amdgcn_global_load_lds((const __attribute__((address_space(1))) void*)ga,
                                             (__attribute__((address_space(3))) void*)la, 16, 0, 0);
            const u16* gb = Bp + (size_t)(n0 + r) * D_MODEL + k0 + c8 * 8;
            char* lb = (char*)Bs + (it * 256 + w * 64) * 16;
            __builtin_amdgcn_global_load_lds((const __attribute__((address_space(1))) void*)gb,
                                             (__attribute__((address_space(3))) void*)lb, 16, 0, 0);
        }
        __syncthreads();

        #pragma unroll
        for (int kc = 0; kc < 2; ++kc) {
            frag_ab av[4], bvv[4];
            #pragma unroll
            for (int i = 0; i < 4; i++)
                av[i] = *(const frag_ab*)&As[(wm + i * 16 + lrow) * BK + kc * 32 + lquad * 8];
            #pragma unroll
            for (int j = 0; j < 4; j++)
                bvv[j] = *(const frag_ab*)&Bs[(wn + j * 16 + lrow) * BK + kc * 32 + lquad * 8];
            #pragma unroll
            for (int i = 0; i < 4; i++)
                #pragma unroll
                for (int j = 0; j < 4; j++)
                    acc[i][j] = __builtin_amdgcn_mfma_f32_16x16x32_bf16(av[i], bvv[j], acc[i][j], 0, 0, 0);
        }
    }

    const float scale = (!vt && z == 0) ? QSCALE : 1.0f;
    #pragma unroll
    for (int j = 0; j < 4; j++) {
        int gn = n0 + wn + j * 16 + lrow;
        #pragma unroll
        for (int i = 0; i < 4; i++) {
            #pragma unroll
            for (int rr = 0; rr < 4; ++rr) {
                int gm = m0 + wm + i * 16 + lquad * 4 + rr;
                if (!vt) {
                    float v = (acc[i][j][rr] + bias[gn]) * scale;
                    u16* oz = QKw + (size_t)z * ((size_t)MTOT * D_MODEL);
                    int b = gm >> 11, s = gm & (SEQ - 1);
                    int h = gn >> 6, d = gn & (HDIM - 1);
                    oz[(((size_t)(b * NHEAD + h)) * SEQ + s) * HDIM + d] = f2u(v);
                } else {
                    float v = acc[i][j][rr] + bias[gm];
                    int h = gm >> 6, d = gm & (HDIM - 1);
                    int b = gn >> 11, s = gn & (SEQ - 1);
                    Vtw[(((size_t)(b * NHEAD + h)) * HDIM + d) * SEQ + s] = f2u(v);
                }
            }
        }
    }
}

// ---------------------------------------------------------------------------
// Out projection: 64x128 tile (512 blocks), fp32 store. XCD swizzle: each XCD
// owns 8 consecutive m-tiles x all 8 n-tiles (Wo slab L2-resident).
// ---------------------------------------------------------------------------
__launch_bounds__(256, 2)
__global__ void gemm_out(const u16* __restrict__ A, const u16* __restrict__ Wt,
                         const float* __restrict__ bias, float* __restrict__ out) {
    constexpr int BK = 64;
    __shared__ __attribute__((aligned(16))) u16 As[64 * BK];
    __shared__ __attribute__((aligned(16))) u16 Bs[128 * BK];

    const int tid = threadIdx.x;
    const int w = tid >> 6;
    const int lane = tid & 63;
    const int lrow = lane & 15, lquad = lane >> 4;
    const int L0 = blockIdx.y * 8 + blockIdx.x;      // dispatch-linear 0..511
    const int L = (L0 & 7) * 64 + (L0 >> 3);         // XCD-chunked, bijective on 512
    const int m0 = (L >> 3) * 64, n0 = (L & 7) * 128;

    frag_cd acc[2][4];
    #pragma unroll
    for (int i = 0; i < 2; i++)
        #pragma unroll
        for (int j = 0; j < 4; j++) acc[i][j] = (frag_cd){0.f, 0.f, 0.f, 0.f};

    const int wm = (w >> 1) * 32, wn = (w & 1) * 64;

    for (int k0 = 0; k0 < D_MODEL; k0 += BK) {
        __syncthreads();
        #pragma unroll
        for (int it = 0; it < 2; ++it) {
            int c = it * 256 + tid;
            int r = c >> 3, c8 = c & 7;
            const u16* ga = A + (size_t)(m0 + r) * D_MODEL + k0 + c8 * 8;
            char* la = (char*)As + (it * 256 + w * 64) * 16;
            __builtin_amdgcn_global_load_lds((const __attribute__((address_space(1))) void*)ga,
                                             (__attribute__((address_space(3))) void*)la, 16, 0, 0);
        }
        #pragma unroll
        for (int it = 0; it < 4; ++it) {
            int c = it * 256 + tid;
            int r = c >> 3, c8 = c & 7;
            const u16* gb = Wt + (size_t)(n0 + r) * D_MODEL + k0 + c8 * 8;
            char* lb = (char*)Bs + (it * 256 + w * 64) * 16;
            __builtin_amdgcn_global_load_lds((const __attribute__((address_space(1))) void*)gb,
                                             (__attribute__((address_space(3))) void*)lb, 16, 0, 0);
        }
        __syncthreads();

        #pragma unroll
        for (int kc = 0; kc < 2; ++kc) {
            frag_ab av[2], bvv[4];
            #pragma unroll
            for (int i = 0; i < 2; i++)
                av[i] = *(const frag_ab*)&As[(wm + i * 16 + lrow) * BK + kc * 32 + lquad * 8];
            #pragma unroll
            for (int j = 0; j < 4; j++)
                bvv[j] = *(const frag_ab*)&Bs[(wn + j * 16 + lrow) * BK + kc * 32 + lquad * 8];
            #pragma unroll
            for (int i = 0; i < 2; i++)
                #pragma unroll
                for (int j = 0; j < 4; j++)
                    acc[i][j] = __builtin_amdgcn_mfma_f32_16x16x32_bf16(av[i], bvv[j], acc[i][j], 0, 0, 0);
        }
    }

    #pragma unroll
    for (int j = 0; j < 4; j++) {
        int gn = n0 + wn + j * 16 + lrow;
        float bvf = bias[gn];
        #pragma unroll
        for (int i = 0; i < 2; i++)
            #pragma unroll
            for (int rr = 0; rr < 4; ++rr) {
                int gm = m0 + wm + i * 16 + lquad * 4 + rr;
                out[(size_t)gm * D_MODEL + gn] = acc[i][j][rr] + bvf;
            }
    }
}

// ---------------------------------------------------------------------------
// Attention, R14 (= R13 + XCD swizzle + setprio). Grid (32,32), 512 thr,
// 8 waves: wave w -> q-group qg=w&3 (16 q), key-half kh=w>>2. Single-buffered
// 32KB LDS, global_load_lds staging with source-side XOR swizzle. Partial
// O^T + rowsum combined additively via LDS. exp via raw v_exp_f32.
// XCD swizzle: each XCD owns 4 bh (2MB K/V L2-resident).
// ---------------------------------------------------------------------------
__launch_bounds__(512, 8)
__global__ void attn_kernel(const u16* __restrict__ Q, const u16* __restrict__ K,
                            const u16* __restrict__ Vt, u16* __restrict__ O) {
    __shared__ __attribute__((aligned(16))) u16 SMEM[16384];  // 32 KB
    u16* Ks = SMEM;            // [128 keys][64 d], source-swizzled chunks
    u16* Vs = SMEM + 8192;     // [64 d][128 keys], source-swizzled chunks

    const int tid = threadIdx.x;
    const int w = tid >> 6;           // 8 waves
    const int lane = tid & 63;
    const int lrow = lane & 15, lquad = lane >> 4;
    const int qg = w & 3;             // q-group (16 q)
    const int kh = w >> 2;            // key half: 0 -> keys [0,64), 1 -> [64,128)

    // XCD-chunked bijective block map: XCD x owns bh = 4x..4x+3, all 32 q-tiles
    const int L = blockIdx.y * 32 + blockIdx.x;      // dispatch-linear 0..1023
    const int xcd = L & 7, off = L >> 3;             // off 0..127
    const int bh = xcd * 4 + (off >> 5);             // 0..31
    const int q0 = (off & 31) * 64;

    const size_t base = (size_t)bh * SEQ * HDIM;
    const u16* Qg = Q + base;
    const u16* Kg = K + base;
    const u16* Vg = Vt + base;  // [d][s]

    // Q as B-operand of 16x16x32: lane holds q = lrow, d = kc*32 + lquad*8 + j
    frag_ab qf[2];
    #pragma unroll
    for (int kc = 0; kc < 2; ++kc)
        qf[kc] = *(const frag_ab*)&Qg[(size_t)(q0 + qg * 16 + lrow) * HDIM + kc * 32 + lquad * 8];

    frag_cd accOT[4];   // partial O^T: lane q = lrow, d = df*16 + lquad*4 + i
    #pragma unroll
    for (int df = 0; df < 4; df++) accOT[df] = (frag_cd){0.f, 0.f, 0.f, 0.f};
    f32x2 lacc2 = (f32x2){0.f, 0.f};  // packed rowsum partial

    // ---- hoisted staging addresses (kt-invariant except constant stride) ----
    const int c0 = tid, c1 = 512 + tid;
    const u16* gk0 = Kg + ((c0 >> 3) * HDIM + (((c0 & 7) ^ ((c0 >> 3) & 7)) << 3));
    const u16* gk1 = Kg + ((c1 >> 3) * HDIM + (((c1 & 7) ^ ((c1 >> 3) & 7)) << 3));
    const u16* gv0 = Vg + ((size_t)(c0 >> 4) * SEQ + (((c0 & 15) ^ ((c0 >> 4) & 7)) << 3));
    const u16* gv1 = Vg + ((size_t)(c1 >> 4) * SEQ + (((c1 & 15) ^ ((c1 >> 4) & 7)) << 3));
    char* lk0 = (char*)Ks + (0 * 512 + w * 64) * 16;   // + implicit lane*16
    char* lk1 = (char*)Ks + (1 * 512 + w * 64) * 16;
    char* lv0 = (char*)Vs + (0 * 512 + w * 64) * 16;
    char* lv1 = (char*)Vs + (1 * 512 + w * 64) * 16;

    // ---- hoisted LDS fragment base pointers (kt-invariant) ----
    const u16* kb0 = Ks + (kh * 64 + lrow) * 64 + (((0 + lquad) ^ (lrow & 7)) << 3);
    const u16* kb1 = Ks + (kh * 64 + lrow) * 64 + (((4 + lquad) ^ (lrow & 7)) << 3);
    const u16* vb[4];
    #pragma unroll
    for (int cm = 0; cm < 4; ++cm) {
        const int gc = ((kh * 4 + cm) << 1) + (lquad >> 1);
        vb[cm] = Vs + lrow * 128 + ((gc ^ (lrow & 7)) << 3) + (lquad & 1) * 4;
    }

    for (int kt = 0; kt < SEQ / 128; ++kt) {
        __syncthreads();   // all reads of SMEM done
        __builtin_amdgcn_global_load_lds((const __attribute__((address_space(1))) void*)gk0,
                                         (__attribute__((address_space(3))) void*)lk0, 16, 0, 0);
        __builtin_amdgcn_global_load_lds((const __attribute__((address_space(1))) void*)gk1,
                                         (__attribute__((address_space(3))) void*)lk1, 16, 0, 0);
        __builtin_amdgcn_global_load_lds((const __attribute__((address_space(1))) void*)gv0,
                                         (__attribute__((address_space(3))) void*)lv0, 16, 0, 0);
        __builtin_amdgcn_global_load_lds((const __attribute__((address_space(1))) void*)gv1,
                                         (__attribute__((address_space(3))) void*)lv1, 16, 0, 0);
        gk0 += 128 * HDIM; gk1 += 128 * HDIM;   // next 128-key tile
        gv0 += 128;        gv1 += 128;
        __syncthreads();   // drain vmcnt, tile visible

        // this wave's 64 keys, in 2 chunks of 32 to cap live registers
        #pragma unroll
        for (int ch = 0; ch < 2; ++ch) {
            frag_cd sc[2];
            #pragma unroll
            for (int m = 0; m < 2; m++) sc[m] = (frag_cd){0.f, 0.f, 0.f, 0.f};
            __builtin_amdgcn_s_setprio(1);
            #pragma unroll
            for (int m = 0; m < 2; m++) {
                frag_ab kf0 = *(const frag_ab*)(kb0 + (ch * 2 + m) * 1024);
                sc[m] = __builtin_amdgcn_mfma_f32_16x16x32_bf16(kf0, qf[0], sc[m], 0, 0, 0);
                frag_ab kf1 = *(const frag_ab*)(kb1 + (ch * 2 + m) * 1024);
                sc[m] = __builtin_amdgcn_mfma_f32_16x16x32_bf16(kf1, qf[1], sc[m], 0, 0, 0);
            }
            __builtin_amdgcn_s_setprio(0);

            frag_s4 pk[2];
            #pragma unroll
            for (int m = 0; m < 2; m++) {
                float e0 = fexp2(sc[m][0]), e1 = fexp2(sc[m][1]);
                float e2 = fexp2(sc[m][2]), e3 = fexp2(sc[m][3]);
                f32x2 a = {e0, e1}, b2 = {e2, e3};
                lacc2 += a + b2;  // v_pk_add_f32
                union { frag_s4 s; unsigned int u[2]; } pu;
                pu.u[0] = pkrn(e0, e1);
                pu.u[1] = pkrn(e2, e3);
                pk[m] = pu.s;
            }

            // O^T += V^T . P^T : A = V^T (m=d, k=this wave's keys, swizzled b64)
            __builtin_amdgcn_s_setprio(1);
            #pragma unroll
            for (int m = 0; m < 2; m++) {
                const u16* vp = vb[ch * 2 + m];
                #pragma unroll
                for (int df = 0; df < 4; df++) {
                    frag_s4 vf = *(const frag_s4*)(vp + df * 2048);
                    accOT[df] = __builtin_amdgcn_mfma_f32_16x16x16bf16_1k(vf, pk[m], accOT[df], 0, 0, 0);
                }
            }
            __builtin_amdgcn_s_setprio(0);
        }
    }

    // rowsum: pack-halves + quad reduce (lanes lrow, +16, +32, +48 hold same q)
    float lacc = lacc2[0] + lacc2[1];
    lacc += __shfl_xor(lacc, 16);
    lacc += __shfl_xor(lacc, 32);

    // combine key-halves additively via LDS (reuse SMEM; stride 68 spreads banks)
    float* comb = (float*)SMEM;              // [64 q][68], 17408 B
    float* lsum = (float*)SMEM + 64 * 68;    // 64 f32
    __syncthreads();   // all tile reads done before overwrite
    if (kh) {
        float* crow = comb + (qg * 16 + lrow) * 68;
        #pragma unroll
        for (int df = 0; df < 4; df++)
            *(float4*)&crow[df * 16 + lquad * 4] =
                (float4){accOT[df][0], accOT[df][1], accOT[df][2], accOT[df][3]};
        if (lquad == 0) lsum[qg * 16 + lrow] = lacc;
    }
    __syncthreads();
    if (!kh) {
        const float* crow = comb + (qg * 16 + lrow) * 68;
        #pragma unroll
        for (int df = 0; df < 4; df++) {
            float4 c = *(const float4*)&crow[df * 16 + lquad * 4];
            accOT[df][0] += c.x; accOT[df][1] += c.y;
            accOT[df][2] += c.z; accOT[df][3] += c.w;
        }
        lacc += lsum[qg * 16 + lrow];

        // epilogue: lane owns one q -> single reciprocal; b64 stores (packed cvt)
        const int b = bh >> 4, h = bh & (NHEAD - 1);
        const int s = q0 + qg * 16 + lrow;
        const float inv = 1.0f / lacc;
        u16* orow = O + ((size_t)(b * SEQ + s)) * D_MODEL + h * HDIM;
        #pragma unroll
        for (int df = 0; df < 4; df++) {
            union { unsigned int u[2]; ushort4 s4; } o;
            o.u[0] = pkrn(accOT[df][0] * inv, accOT[df][1] * inv);
            o.u[1] = pkrn(accOT[df][2] * inv, accOT[df][3] * inv);
            *(ushort4*)&orow[df * 16 + lquad * 4] = o.s4;
        }
    }
}

// ---------------------------------------------------------------------------
// Workspace (u16 elems): xb [0,4M) | Wt 4 slabs [4M,8M) | Q,K [8M,16M)
//                        Vt [16M,20M) | attn-out [20M,24M)   = 48 MB
// ---------------------------------------------------------------------------
extern "C" void kernel_launch(void* const* d_in, const int* in_sizes, int n_in,
                              void* d_out, int out_size, void* d_ws, size_t ws_size,
                              hipStream_t stream) {
    const float* x  = (const float*)d_in[0];
    const float* Wq = (const float*)d_in[1];
    const float* bq = (const float*)d_in[2];
    const float* Wk = (const float*)d_in[3];
    const float* bk = (const float*)d_in[4];
    const float* Wv = (const float*)d_in[5];
    const float* bv = (const float*)d_in[6];
    const float* Wo = (const float*)d_in[7];
    const float* bo = (const float*)d_in[8];

    u16* ws = (u16*)d_ws;
    const size_t WSZ = (size_t)D_MODEL * D_MODEL;    // 1M elems
    const size_t TSZ = (size_t)MTOT * D_MODEL;       // 4M elems
    u16* xb  = ws;
    u16* Wt  = ws + 4 * WSZ;
    u16* QKw = ws + 8 * WSZ;        // Q slab 0, K slab 1
    u16* Vtw = QKw + 2 * TSZ;
    u16* Aw  = Vtw + TSZ;

    prep<<<dim3(32, 32, 5), dim3(32, 8), 0, stream>>>(Wq, Wk, Wv, Wo, x, Wt, xb);
    gemm_qkvt<<<dim3(768), 256, 0, stream>>>(xb, Wt, bq, bk, bv, QKw, Vtw);
    attn_kernel<<<dim3(32, 32), 512, 0, stream>>>(QKw, QKw + TSZ, Vtw, Aw);
    gemm_out<<<dim3(8, 64), 256, 0, stream>>>(Aw, Wt + 3 * WSZ, bo, (float*)d_out);
}

// Round 6
// 208.520 us; speedup vs baseline: 1.1146x; 1.0118x over previous
//
#include <hip/hip_runtime.h>
#include <hip/hip_bf16.h>

// MultiBertAttention fp32 I/O, bf16 MFMA internals.
// R15: attn is LDS-PIPE-bound (arithmetic: 41us reads + 7us writes + 14us
//      conflicts ~= the whole 60us kernel; R14's FETCH drop 72->12MB with no
//      speedup rules out HBM; R12 rules out occupancy). Fix: halve LDS read
//      traffic per q at constant wave shape: 8 waves = 4 qg x 2 kh, each wave
//      owns TWO 16-q fragments (32 q) -> every K/V LDS fragment feeds 2 MFMAs.
//      Block covers 128 q -> 512 blocks (2/CU), __launch_bounds__(512,4)
//      (16 waves/CU, VGPR<=128). Same staging/swizzles/layouts as R14.
//      kh-combine epilogue extended to 128 q (SMEM 35.3KB).
//      prep / gemm_qkvt / gemm_out unchanged from R14.

typedef unsigned short u16;

#define D_MODEL 1024
#define NHEAD 16
#define HDIM 64
#define BATCH 2
#define SEQ 2048
#define MTOT (BATCH * SEQ)  // 4096

#define QSCALE 0.18033688011112042f  // (1/8) * log2(e)

using frag_ab = __attribute__((ext_vector_type(8))) short;  // 8 bf16 (16x16x32 A/B)
using frag_s4 = __attribute__((ext_vector_type(4))) short;  // 4 bf16 (16x16x16 A/B)
using frag_cd = __attribute__((ext_vector_type(4))) float;  // 4 fp32
using f32x2   = __attribute__((ext_vector_type(2))) float;

__device__ __forceinline__ u16 f2u(float f) {  // RNE fp32->bf16
    union { float f; unsigned int i; } x;
    x.f = f;
    unsigned int r = x.i + 0x7fffu + ((x.i >> 16) & 1u);
    return (u16)(r >> 16);
}
__device__ __forceinline__ unsigned int pkrn(float a, float b) {  // v_cvt_pk_bf16_f32
    union { __hip_bfloat162 h; unsigned int u; } c;
    c.h = __float22bfloat162_rn(float2{a, b});
    return c.u;
}
__device__ __forceinline__ float fexp2(float x) {  // raw v_exp_f32 (inputs bounded)
#if __has_builtin(__builtin_amdgcn_exp2f)
    return __builtin_amdgcn_exp2f(x);
#else
    float r;
    asm("v_exp_f32 %0, %1" : "=v"(r) : "v"(x));
    return r;
#endif
}

// ---------------------------------------------------------------------------
// prep: z<4 -> Wt[z][n][k] = bf16(W_z[k][n]); z==4 -> xb = bf16(x).
// Write phase: one ushort4 (4 k's) store per thread.
// ---------------------------------------------------------------------------
__global__ void prep(const float* __restrict__ W0, const float* __restrict__ W1,
                     const float* __restrict__ W2, const float* __restrict__ W3,
                     const float* __restrict__ X, u16* __restrict__ Wt,
                     u16* __restrict__ Xb) {
    const int z = blockIdx.z;
    const int tx = threadIdx.x, ty = threadIdx.y;
    const int tid = ty * 32 + tx;
    if (z < 4) {
        __shared__ u16 t[32][33];   // t[k_local][n_local]
        const float* W = (z == 0) ? W0 : (z == 1) ? W1 : (z == 2) ? W2 : W3;
        u16* o = Wt + (size_t)z * D_MODEL * D_MODEL;
        int n0 = blockIdx.x * 32, k0 = blockIdx.y * 32;
        #pragma unroll
        for (int i = ty; i < 32; i += 8) t[i][tx] = f2u(W[(size_t)(k0 + i) * D_MODEL + n0 + tx]);
        __syncthreads();
        const int r = tid >> 3, c = tid & 7;   // out row n = r, k-group = c
        ushort4 o4;
        o4.x = t[4 * c + 0][r]; o4.y = t[4 * c + 1][r];
        o4.z = t[4 * c + 2][r]; o4.w = t[4 * c + 3][r];
        *(ushort4*)&o[(size_t)(n0 + r) * D_MODEL + k0 + 4 * c] = o4;
    } else {
        size_t base = ((size_t)(blockIdx.y * 32 + blockIdx.x) * 256 + tid) * 16;
        #pragma unroll
        for (int c = 0; c < 4; ++c) {
            float4 v = *(const float4*)&X[base + c * 4];
            ushort4 o;
            o.x = f2u(v.x); o.y = f2u(v.y); o.z = f2u(v.z); o.w = f2u(v.w);
            *(ushort4*)&Xb[base + c * 4] = o;
        }
    }
}

// ---------------------------------------------------------------------------
// Fused QKV + V^T GEMM, 768 blocks (1D). 128x128 tile, BK=64, global_load_lds.
// XCD swizzle: bid=(b&7)*96+(b>>3).
// ---------------------------------------------------------------------------
__launch_bounds__(256, 3)
__global__ void gemm_qkvt(const u16* __restrict__ xb, const u16* __restrict__ Wt,
                          const float* __restrict__ bq, const float* __restrict__ bk,
                          const float* __restrict__ bv, u16* __restrict__ QKw,
                          u16* __restrict__ Vtw) {
    constexpr int BK = 64;
    __shared__ __attribute__((aligned(16))) u16 As[128 * BK];
    __shared__ __attribute__((aligned(16))) u16 Bs[128 * BK];

    const int tid = threadIdx.x;
    const int w = tid >> 6;
    const int lane = tid & 63;
    const int lrow = lane & 15, lquad = lane >> 4;
    const size_t WSZ = (size_t)D_MODEL * D_MODEL;

    const int bid0 = blockIdx.x;
    const int bid = (bid0 & 7) * 96 + (bid0 >> 3);   // XCD-chunked, bijective on 768
    const bool vt = bid >= 512;
    const int z = vt ? 2 : (bid >> 8);
    const int t = vt ? (bid - 512) : (bid & 255);
    const int n0 = vt ? (t & 31) * 128 : (t & 7) * 128;
    const int m0 = vt ? (t >> 5) * 128 : (t >> 3) * 128;
    const u16* Ap = vt ? (Wt + 2 * WSZ) : xb;
    const u16* Bp = vt ? xb : (Wt + (size_t)z * WSZ);
    const float* bias = vt ? bv : (z ? bk : bq);

    frag_cd acc[4][4];
    #pragma unroll
    for (int i = 0; i < 4; i++)
        #pragma unroll
        for (int j = 0; j < 4; j++) acc[i][j] = (frag_cd){0.f, 0.f, 0.f, 0.f};

    const int wm = (w >> 1) * 64, wn = (w & 1) * 64;

    for (int k0 = 0; k0 < D_MODEL; k0 += BK) {
        __syncthreads();
        #pragma unroll
        for (int it = 0; it < 4; ++it) {
            int c = it * 256 + tid;
            int r = c >> 3, c8 = c & 7;
            const u16* ga = Ap + (size_t)(m0 + r) * D_MODEL + k0 + c8 * 8;
            char* la = (char*)As + (it * 256 + w * 64) * 16;
            __builtin_amdgcn_global_load_lds((const __attribute__((address_space(1))) void*)ga,
                                             (__attribute__((address_space(3))) void*)la, 16, 0, 0);
            const u16* gb = Bp + (size_t)(n0 + r) * D_MODEL + k0 + c8 * 8;
            char* lb = (char*)Bs + (it * 256 + w * 64) * 16;
            __builtin_amdgcn_global_load_lds((const __attribute__((address_space(1))) void*)gb,
                                             (__attribute__((address_space(3))) void*)lb, 16, 0, 0);
        }
        __syncthreads();

        #pragma unroll
        for (int kc = 0; kc < 2; ++kc) {
            frag_ab av[4], bvv[4];
            #pragma unroll
            for (int i = 0; i < 4; i++)
                av[i] = *(const frag_ab*)&As[(wm + i * 16 + lrow) * BK + kc * 32 + lquad * 8];
            #pragma unroll
            for (int j = 0; j < 4; j++)
                bvv[j] = *(const frag_ab*)&Bs[(wn + j * 16 + lrow) * BK + kc * 32 + lquad * 8];
            #pragma unroll
            for (int i = 0; i < 4; i++)
                #pragma unroll
                for (int j = 0; j < 4; j++)
                    acc[i][j] = __builtin_amdgcn_mfma_f32_16x16x32_bf16(av[i], bvv[j], acc[i][j], 0, 0, 0);
        }
    }

    const float scale = (!vt && z == 0) ? QSCALE : 1.0f;
    #pragma unroll
    for (int j = 0; j < 4; j++) {
        int gn = n0 + wn + j * 16 + lrow;
        #pragma unroll
        for (int i = 0; i < 4; i++) {
            #pragma unroll
            for (int rr = 0; rr < 4; ++rr) {
                int gm = m0 + wm + i * 16 + lquad * 4 + rr;
                if (!vt) {
                    float v = (acc[i][j][rr] + bias[gn]) * scale;
                    u16* oz = QKw + (size_t)z * ((size_t)MTOT * D_MODEL);
                    int b = gm >> 11, s = gm & (SEQ - 1);
                    int h = gn >> 6, d = gn & (HDIM - 1);
                    oz[(((size_t)(b * NHEAD + h)) * SEQ + s) * HDIM + d] = f2u(v);
                } else {
                    float v = acc[i][j][rr] + bias[gm];
                    int h = gm >> 6, d = gm & (HDIM - 1);
                    int b = gn >> 11, s = gn & (SEQ - 1);
                    Vtw[(((size_t)(b * NHEAD + h)) * HDIM + d) * SEQ + s] = f2u(v);
                }
            }
        }
    }
}

// ---------------------------------------------------------------------------
// Out projection: 64x128 tile (512 blocks), fp32 store. XCD swizzle.
// ---------------------------------------------------------------------------
__launch_bounds__(256, 2)
__global__ void gemm_out(const u16* __restrict__ A, const u16* __restrict__ Wt,
                         const float* __restrict__ bias, float* __restrict__ out) {
    constexpr int BK = 64;
    __shared__ __attribute__((aligned(16))) u16 As[64 * BK];
    __shared__ __attribute__((aligned(16))) u16 Bs[128 * BK];

    const int tid = threadIdx.x;
    const int w = tid >> 6;
    const int lane = tid & 63;
    const int lrow = lane & 15, lquad = lane >> 4;
    const int L0 = blockIdx.y * 8 + blockIdx.x;      // dispatch-linear 0..511
    const int L = (L0 & 7) * 64 + (L0 >> 3);         // XCD-chunked, bijective on 512
    const int m0 = (L >> 3) * 64, n0 = (L & 7) * 128;

    frag_cd acc[2][4];
    #pragma unroll
    for (int i = 0; i < 2; i++)
        #pragma unroll
        for (int j = 0; j < 4; j++) acc[i][j] = (frag_cd){0.f, 0.f, 0.f, 0.f};

    const int wm = (w >> 1) * 32, wn = (w & 1) * 64;

    for (int k0 = 0; k0 < D_MODEL; k0 += BK) {
        __syncthreads();
        #pragma unroll
        for (int it = 0; it < 2; ++it) {
            int c = it * 256 + tid;
            int r = c >> 3, c8 = c & 7;
            const u16* ga = A + (size_t)(m0 + r) * D_MODEL + k0 + c8 * 8;
            char* la = (char*)As + (it * 256 + w * 64) * 16;
            __builtin_amdgcn_global_load_lds((const __attribute__((address_space(1))) void*)ga,
                                             (__attribute__((address_space(3))) void*)la, 16, 0, 0);
        }
        #pragma unroll
        for (int it = 0; it < 4; ++it) {
            int c = it * 256 + tid;
            int r = c >> 3, c8 = c & 7;
            const u16* gb = Wt + (size_t)(n0 + r) * D_MODEL + k0 + c8 * 8;
            char* lb = (char*)Bs + (it * 256 + w * 64) * 16;
            __builtin_amdgcn_global_load_lds((const __attribute__((address_space(1))) void*)gb,
                                             (__attribute__((address_space(3))) void*)lb, 16, 0, 0);
        }
        __syncthreads();

        #pragma unroll
        for (int kc = 0; kc < 2; ++kc) {
            frag_ab av[2], bvv[4];
            #pragma unroll
            for (int i = 0; i < 2; i++)
                av[i] = *(const frag_ab*)&As[(wm + i * 16 + lrow) * BK + kc * 32 + lquad * 8];
            #pragma unroll
            for (int j = 0; j < 4; j++)
                bvv[j] = *(const frag_ab*)&Bs[(wn + j * 16 + lrow) * BK + kc * 32 + lquad * 8];
            #pragma unroll
            for (int i = 0; i < 2; i++)
                #pragma unroll
                for (int j = 0; j < 4; j++)
                    acc[i][j] = __builtin_amdgcn_mfma_f32_16x16x32_bf16(av[i], bvv[j], acc[i][j], 0, 0, 0);
        }
    }

    #pragma unroll
    for (int j = 0; j < 4; j++) {
        int gn = n0 + wn + j * 16 + lrow;
        float bvf = bias[gn];
        #pragma unroll
        for (int i = 0; i < 2; i++)
            #pragma unroll
            for (int rr = 0; rr < 4; ++rr) {
                int gm = m0 + wm + i * 16 + lquad * 4 + rr;
                out[(size_t)gm * D_MODEL + gn] = acc[i][j][rr] + bvf;
            }
    }
}

// ---------------------------------------------------------------------------
// Attention, R15: grid (16,32) = 512 blocks (2/CU), 512 thr = 8 waves
// (4 qg x 2 kh). Each wave owns TWO 16-q fragments (groups qg and qg+4 of the
// 128-q tile) x 64 keys -> every K/V LDS fragment feeds 2 MFMAs; per-CU LDS
// read traffic HALVED vs R14 (the measured bottleneck). Single-buffered 32KB
// staging (global_load_lds, source-side XOR swizzle). kh-partials combined
// additively via LDS. exp via raw v_exp_f32; setprio around MFMA clusters.
// XCD swizzle: each XCD owns 4 bh.
// ---------------------------------------------------------------------------
__launch_bounds__(512, 4)
__global__ void attn_kernel(const u16* __restrict__ Q, const u16* __restrict__ K,
                            const u16* __restrict__ Vt, u16* __restrict__ O) {
    __shared__ __attribute__((aligned(16))) u16 SMEM[17664];  // 35.3 KB
    u16* Ks = SMEM;            // [128 keys][64 d], source-swizzled chunks
    u16* Vs = SMEM + 8192;     // [64 d][128 keys], source-swizzled chunks

    const int tid = threadIdx.x;
    const int w = tid >> 6;           // 8 waves
    const int lane = tid & 63;
    const int lrow = lane & 15, lquad = lane >> 4;
    const int qg = w & 3;             // q-group pair: groups qg, qg+4
    const int kh = w >> 2;            // key half: 0 -> keys [0,64), 1 -> [64,128)

    // XCD-chunked bijective block map: XCD x owns bh = 4x..4x+3, 16 q-tiles each
    const int L = blockIdx.y * 16 + blockIdx.x;      // dispatch-linear 0..511
    const int xcd = L & 7, off = L >> 3;             // off 0..63
    const int bh = xcd * 4 + (off >> 4);             // 0..31
    const int q0 = (off & 15) * 128;

    const size_t base = (size_t)bh * SEQ * HDIM;
    const u16* Qg = Q + base;
    const u16* Kg = K + base;
    const u16* Vg = Vt + base;  // [d][s]

    // Q as B-operand of 16x16x32: lane holds q = lrow, d = kc*32 + lquad*8 + j
    frag_ab qf[2][2];   // [group g][kc]
    #pragma unroll
    for (int g = 0; g < 2; ++g)
        #pragma unroll
        for (int kc = 0; kc < 2; ++kc)
            qf[g][kc] = *(const frag_ab*)&Qg[(size_t)(q0 + (qg + g * 4) * 16 + lrow) * HDIM + kc * 32 + lquad * 8];

    frag_cd accOT[2][4];   // [group][df]: partial O^T, lane q = lrow, d = df*16+lquad*4+i
    #pragma unroll
    for (int g = 0; g < 2; ++g)
        #pragma unroll
        for (int df = 0; df < 4; df++) accOT[g][df] = (frag_cd){0.f, 0.f, 0.f, 0.f};
    f32x2 la0 = (f32x2){0.f, 0.f}, la1 = (f32x2){0.f, 0.f};  // packed rowsum partials

    // ---- hoisted staging addresses (kt-invariant except constant stride) ----
    const int c0 = tid, c1 = 512 + tid;
    const u16* gk0 = Kg + ((c0 >> 3) * HDIM + (((c0 & 7) ^ ((c0 >> 3) & 7)) << 3));
    const u16* gk1 = Kg + ((c1 >> 3) * HDIM + (((c1 & 7) ^ ((c1 >> 3) & 7)) << 3));
    const u16* gv0 = Vg + ((size_t)(c0 >> 4) * SEQ + (((c0 & 15) ^ ((c0 >> 4) & 7)) << 3));
    const u16* gv1 = Vg + ((size_t)(c1 >> 4) * SEQ + (((c1 & 15) ^ ((c1 >> 4) & 7)) << 3));
    char* lk0 = (char*)Ks + (0 * 512 + w * 64) * 16;   // + implicit lane*16
    char* lk1 = (char*)Ks + (1 * 512 + w * 64) * 16;
    char* lv0 = (char*)Vs + (0 * 512 + w * 64) * 16;
    char* lv1 = (char*)Vs + (1 * 512 + w * 64) * 16;

    // ---- hoisted LDS fragment base pointers (kt-invariant) ----
    const u16* kb0 = Ks + (kh * 64 + lrow) * 64 + (((0 + lquad) ^ (lrow & 7)) << 3);
    const u16* kb1 = Ks + (kh * 64 + lrow) * 64 + (((4 + lquad) ^ (lrow & 7)) << 3);
    const u16* vb[4];
    #pragma unroll
    for (int cm = 0; cm < 4; ++cm) {
        const int gc = ((kh * 4 + cm) << 1) + (lquad >> 1);
        vb[cm] = Vs + lrow * 128 + ((gc ^ (lrow & 7)) << 3) + (lquad & 1) * 4;
    }

    for (int kt = 0; kt < SEQ / 128; ++kt) {
        __syncthreads();   // all reads of SMEM done
        __builtin_amdgcn_global_load_lds((const __attribute__((address_space(1))) void*)gk0,
                                         (__attribute__((address_space(3))) void*)lk0, 16, 0, 0);
        __builtin_amdgcn_global_load_lds((const __attribute__((address_space(1))) void*)gk1,
                                         (__attribute__((address_space(3))) void*)lk1, 16, 0, 0);
        __builtin_amdgcn_global_load_lds((const __attribute__((address_space(1))) void*)gv0,
                                         (__attribute__((address_space(3))) void*)lv0, 16, 0, 0);
        __builtin_amdgcn_global_load_lds((const __attribute__((address_space(1))) void*)gv1,
                                         (__attribute__((address_space(3))) void*)lv1, 16, 0, 0);
        gk0 += 128 * HDIM; gk1 += 128 * HDIM;   // next 128-key tile
        gv0 += 128;        gv1 += 128;
        __syncthreads();   // drain vmcnt, tile visible

        // this wave's 64 keys in 4 fragments of 16; each K/V read feeds 2 q-groups
        #pragma unroll
        for (int cm = 0; cm < 4; ++cm) {
            frag_cd sc0 = (frag_cd){0.f, 0.f, 0.f, 0.f};
            frag_cd sc1 = (frag_cd){0.f, 0.f, 0.f, 0.f};
            __builtin_amdgcn_s_setprio(1);
            {
                frag_ab kf0 = *(const frag_ab*)(kb0 + cm * 1024);
                frag_ab kf1 = *(const frag_ab*)(kb1 + cm * 1024);
                sc0 = __builtin_amdgcn_mfma_f32_16x16x32_bf16(kf0, qf[0][0], sc0, 0, 0, 0);
                sc1 = __builtin_amdgcn_mfma_f32_16x16x32_bf16(kf0, qf[1][0], sc1, 0, 0, 0);
                sc0 = __builtin_amdgcn_mfma_f32_16x16x32_bf16(kf1, qf[0][1], sc0, 0, 0, 0);
                sc1 = __builtin_amdgcn_mfma_f32_16x16x32_bf16(kf1, qf[1][1], sc1, 0, 0, 0);
            }
            __builtin_amdgcn_s_setprio(0);

            frag_s4 pk0, pk1;
            {
                float e0 = fexp2(sc0[0]), e1 = fexp2(sc0[1]);
                float e2 = fexp2(sc0[2]), e3 = fexp2(sc0[3]);
                f32x2 a = {e0, e1}, b2 = {e2, e3};
                la0 += a + b2;
                union { frag_s4 s; unsigned int u[2]; } pu;
                pu.u[0] = pkrn(e0, e1);
                pu.u[1] = pkrn(e2, e3);
                pk0 = pu.s;
            }
            {
                float e0 = fexp2(sc1[0]), e1 = fexp2(sc1[1]);
                float e2 = fexp2(sc1[2]), e3 = fexp2(sc1[3]);
                f32x2 a = {e0, e1}, b2 = {e2, e3};
                la1 += a + b2;
                union { frag_s4 s; unsigned int u[2]; } pu;
                pu.u[0] = pkrn(e0, e1);
                pu.u[1] = pkrn(e2, e3);
                pk1 = pu.s;
            }

            // O^T += V^T . P^T : each V fragment feeds both q-groups
            __builtin_amdgcn_s_setprio(1);
            {
                const u16* vp = vb[cm];
                #pragma unroll
                for (int df = 0; df < 4; df++) {
                    frag_s4 vf = *(const frag_s4*)(vp + df * 2048);
                    accOT[0][df] = __builtin_amdgcn_mfma_f32_16x16x16bf16_1k(vf, pk0, accOT[0][df], 0, 0, 0);
                    accOT[1][df] = __builtin_amdgcn_mfma_f32_16x16x16bf16_1k(vf, pk1, accOT[1][df], 0, 0, 0);
                }
            }
            __builtin_amdgcn_s_setprio(0);
        }
    }

    // rowsums: pack-halves + quad reduce (lanes lrow, +16, +32, +48 hold same q)
    float s0 = la0[0] + la0[1];
    s0 += __shfl_xor(s0, 16);
    s0 += __shfl_xor(s0, 32);
    float s1 = la1[0] + la1[1];
    s1 += __shfl_xor(s1, 16);
    s1 += __shfl_xor(s1, 32);

    // combine key-halves additively via LDS (reuse SMEM; stride 68 spreads banks)
    float* comb = (float*)SMEM;               // [128 q][68], 34816 B
    float* lsum = (float*)SMEM + 128 * 68;    // 128 f32
    __syncthreads();   // all tile reads done before overwrite
    if (kh) {
        #pragma unroll
        for (int g = 0; g < 2; ++g) {
            float* crow = comb + ((qg + g * 4) * 16 + lrow) * 68;
            #pragma unroll
            for (int df = 0; df < 4; df++)
                *(float4*)&crow[df * 16 + lquad * 4] =
                    (float4){accOT[g][df][0], accOT[g][df][1], accOT[g][df][2], accOT[g][df][3]};
        }
        if (lquad == 0) {
            lsum[qg * 16 + lrow] = s0;
            lsum[(qg + 4) * 16 + lrow] = s1;
        }
    }
    __syncthreads();
    if (!kh) {
        const int b = bh >> 4, h = bh & (NHEAD - 1);
        #pragma unroll
        for (int g = 0; g < 2; ++g) {
            const float* crow = comb + ((qg + g * 4) * 16 + lrow) * 68;
            #pragma unroll
            for (int df = 0; df < 4; df++) {
                float4 c = *(const float4*)&crow[df * 16 + lquad * 4];
                accOT[g][df][0] += c.x; accOT[g][df][1] += c.y;
                accOT[g][df][2] += c.z; accOT[g][df][3] += c.w;
            }
            float lacc = (g ? s1 : s0) + lsum[(qg + g * 4) * 16 + lrow];

            // epilogue: lane owns one q per group -> single reciprocal; b64 stores
            const int s = q0 + (qg + g * 4) * 16 + lrow;
            const float inv = 1.0f / lacc;
            u16* orow = O + ((size_t)(b * SEQ + s)) * D_MODEL + h * HDIM;
            #pragma unroll
            for (int df = 0; df < 4; df++) {
                union { unsigned int u[2]; ushort4 s4; } o;
                o.u[0] = pkrn(accOT[g][df][0] * inv, accOT[g][df][1] * inv);
                o.u[1] = pkrn(accOT[g][df][2] * inv, accOT[g][df][3] * inv);
                *(ushort4*)&orow[df * 16 + lquad * 4] = o.s4;
            }
        }
    }
}

// ---------------------------------------------------------------------------
// Workspace (u16 elems): xb [0,4M) | Wt 4 slabs [4M,8M) | Q,K [8M,16M)
//                        Vt [16M,20M) | attn-out [20M,24M)   = 48 MB
// ---------------------------------------------------------------------------
extern "C" void kernel_launch(void* const* d_in, const int* in_sizes, int n_in,
                              void* d_out, int out_size, void* d_ws, size_t ws_size,
                              hipStream_t stream) {
    const float* x  = (const float*)d_in[0];
    const float* Wq = (const float*)d_in[1];
    const float* bq = (const float*)d_in[2];
    const float* Wk = (const float*)d_in[3];
    const float* bk = (const float*)d_in[4];
    const float* Wv = (const float*)d_in[5];
    const float* bv = (const float*)d_in[6];
    const float* Wo = (const float*)d_in[7];
    const float* bo = (const float*)d_in[8];

    u16* ws = (u16*)d_ws;
    const size_t WSZ = (size_t)D_MODEL * D_MODEL;    // 1M elems
    const size_t TSZ = (size_t)MTOT * D_MODEL;       // 4M elems
    u16* xb  = ws;
    u16* Wt  = ws + 4 * WSZ;
    u16* QKw = ws + 8 * WSZ;        // Q slab 0, K slab 1
    u16* Vtw = QKw + 2 * TSZ;
    u16* Aw  = Vtw + TSZ;

    prep<<<dim3(32, 32, 5), dim3(32, 8), 0, stream>>>(Wq, Wk, Wv, Wo, x, Wt, xb);
    gemm_qkvt<<<dim3(768), 256, 0, stream>>>(xb, Wt, bq, bk, bv, QKw, Vtw);
    attn_kernel<<<dim3(16, 32), 512, 0, stream>>>(QKw, QKw + TSZ, Vtw, Aw);
    gemm_out<<<dim3(8, 64), 256, 0, stream>>>(Aw, Wt + 3 * WSZ, bo, (float*)d_out);
}

// Round 7
// 200.962 us; speedup vs baseline: 1.1565x; 1.0376x over previous
//
#include <hip/hip_runtime.h>
#include <hip/hip_bf16.h>

// MultiBertAttention fp32 I/O, bf16 MFMA internals.
// R16: coalesced GEMM epilogues. attn is at its structural floor (~59us:
//      MfmaUtil 35% == issue-cycle model; VALU/LDS/HBM/occupancy all ruled
//      out by R10-R15). The remaining ~150us is the gemms; their epilogues
//      store scalar u16 (qkvt: 64x 2B stores/thread, head-strided) and
//      scalar dwords (gemm_out: 32/thread). Fix: stage C through the free
//      staging LDS (pad-stride) -> 8x 16B stores per thread, bias/scale
//      applied pre-stage. attn / prep unchanged from R15 (verified).

typedef unsigned short u16;

#define D_MODEL 1024
#define NHEAD 16
#define HDIM 64
#define BATCH 2
#define SEQ 2048
#define MTOT (BATCH * SEQ)  // 4096

#define QSCALE 0.18033688011112042f  // (1/8) * log2(e)

using frag_ab = __attribute__((ext_vector_type(8))) short;  // 8 bf16 (16x16x32 A/B)
using frag_s4 = __attribute__((ext_vector_type(4))) short;  // 4 bf16 (16x16x16 A/B)
using frag_cd = __attribute__((ext_vector_type(4))) float;  // 4 fp32
using f32x2   = __attribute__((ext_vector_type(2))) float;
using u16x8   = __attribute__((ext_vector_type(8))) unsigned short;

__device__ __forceinline__ u16 f2u(float f) {  // RNE fp32->bf16
    union { float f; unsigned int i; } x;
    x.f = f;
    unsigned int r = x.i + 0x7fffu + ((x.i >> 16) & 1u);
    return (u16)(r >> 16);
}
__device__ __forceinline__ unsigned int pkrn(float a, float b) {  // v_cvt_pk_bf16_f32
    union { __hip_bfloat162 h; unsigned int u; } c;
    c.h = __float22bfloat162_rn(float2{a, b});
    return c.u;
}
__device__ __forceinline__ float fexp2(float x) {  // raw v_exp_f32 (inputs bounded)
#if __has_builtin(__builtin_amdgcn_exp2f)
    return __builtin_amdgcn_exp2f(x);
#else
    float r;
    asm("v_exp_f32 %0, %1" : "=v"(r) : "v"(x));
    return r;
#endif
}

// ---------------------------------------------------------------------------
// prep: z<4 -> Wt[z][n][k] = bf16(W_z[k][n]); z==4 -> xb = bf16(x).
// ---------------------------------------------------------------------------
__global__ void prep(const float* __restrict__ W0, const float* __restrict__ W1,
                     const float* __restrict__ W2, const float* __restrict__ W3,
                     const float* __restrict__ X, u16* __restrict__ Wt,
                     u16* __restrict__ Xb) {
    const int z = blockIdx.z;
    const int tx = threadIdx.x, ty = threadIdx.y;
    const int tid = ty * 32 + tx;
    if (z < 4) {
        __shared__ u16 t[32][33];   // t[k_local][n_local]
        const float* W = (z == 0) ? W0 : (z == 1) ? W1 : (z == 2) ? W2 : W3;
        u16* o = Wt + (size_t)z * D_MODEL * D_MODEL;
        int n0 = blockIdx.x * 32, k0 = blockIdx.y * 32;
        #pragma unroll
        for (int i = ty; i < 32; i += 8) t[i][tx] = f2u(W[(size_t)(k0 + i) * D_MODEL + n0 + tx]);
        __syncthreads();
        const int r = tid >> 3, c = tid & 7;   // out row n = r, k-group = c
        ushort4 o4;
        o4.x = t[4 * c + 0][r]; o4.y = t[4 * c + 1][r];
        o4.z = t[4 * c + 2][r]; o4.w = t[4 * c + 3][r];
        *(ushort4*)&o[(size_t)(n0 + r) * D_MODEL + k0 + 4 * c] = o4;
    } else {
        size_t base = ((size_t)(blockIdx.y * 32 + blockIdx.x) * 256 + tid) * 16;
        #pragma unroll
        for (int c = 0; c < 4; ++c) {
            float4 v = *(const float4*)&X[base + c * 4];
            ushort4 o;
            o.x = f2u(v.x); o.y = f2u(v.y); o.z = f2u(v.z); o.w = f2u(v.w);
            *(ushort4*)&Xb[base + c * 4] = o;
        }
    }
}

// ---------------------------------------------------------------------------
// Fused QKV + V^T GEMM, 768 blocks (1D). 128x128 tile, BK=64, global_load_lds.
// XCD swizzle bid=(b&7)*96+(b>>3). Epilogue: C staged to LDS [128][136],
// then 8x ushort8 coalesced stores per thread (contiguous along d for Q/K,
// along s for V^T).
// ---------------------------------------------------------------------------
__launch_bounds__(256, 3)
__global__ void gemm_qkvt(const u16* __restrict__ xb, const u16* __restrict__ Wt,
                          const float* __restrict__ bq, const float* __restrict__ bk,
                          const float* __restrict__ bv, u16* __restrict__ QKw,
                          u16* __restrict__ Vtw) {
    constexpr int BK = 64;
    __shared__ __attribute__((aligned(16))) u16 SM[128 * 136];  // 34.8 KB
    u16* As = SM;              // [128][64]
    u16* Bs = SM + 128 * BK;   // [128][64]

    const int tid = threadIdx.x;
    const int w = tid >> 6;
    const int lane = tid & 63;
    const int lrow = lane & 15, lquad = lane >> 4;
    const size_t WSZ = (size_t)D_MODEL * D_MODEL;
    const size_t TSZ = (size_t)MTOT * D_MODEL;

    const int bid0 = blockIdx.x;
    const int bid = (bid0 & 7) * 96 + (bid0 >> 3);   // XCD-chunked, bijective on 768
    const bool vt = bid >= 512;
    const int z = vt ? 2 : (bid >> 8);
    const int t = vt ? (bid - 512) : (bid & 255);
    const int n0 = vt ? (t & 31) * 128 : (t & 7) * 128;
    const int m0 = vt ? (t >> 5) * 128 : (t >> 3) * 128;
    const u16* Ap = vt ? (Wt + 2 * WSZ) : xb;
    const u16* Bp = vt ? xb : (Wt + (size_t)z * WSZ);
    const float* bias = vt ? bv : (z ? bk : bq);

    frag_cd acc[4][4];
    #pragma unroll
    for (int i = 0; i < 4; i++)
        #pragma unroll
        for (int j = 0; j < 4; j++) acc[i][j] = (frag_cd){0.f, 0.f, 0.f, 0.f};

    const int wm = (w >> 1) * 64, wn = (w & 1) * 64;

    for (int k0 = 0; k0 < D_MODEL; k0 += BK) {
        __syncthreads();
        #pragma unroll
        for (int it = 0; it < 4; ++it) {
            int c = it * 256 + tid;
            int r = c >> 3, c8 = c & 7;
            const u16* ga = Ap + (size_t)(m0 + r) * D_MODEL + k0 + c8 * 8;
            char* la = (char*)As + (it * 256 + w * 64) * 16;
            __builtin_amdgcn_global_load_lds((const __attribute__((address_space(1))) void*)ga,
                                             (__attribute__((address_space(3))) void*)la, 16, 0, 0);
            const u16* gb = Bp + (size_t)(n0 + r) * D_MODEL + k0 + c8 * 8;
            char* lb = (char*)Bs + (it * 256 + w * 64) * 16;
            __builtin_amdgcn_global_load_lds((const __attribute__((address_space(1))) void*)gb,
                                             (__attribute__((address_space(3))) void*)lb, 16, 0, 0);
        }
        __syncthreads();

        #pragma unroll
        for (int kc = 0; kc < 2; ++kc) {
            frag_ab av[4], bvv[4];
            #pragma unroll
            for (int i = 0; i < 4; i++)
                av[i] = *(const frag_ab*)&As[(wm + i * 16 + lrow) * BK + kc * 32 + lquad * 8];
            #pragma unroll
            for (int j = 0; j < 4; j++)
                bvv[j] = *(const frag_ab*)&Bs[(wn + j * 16 + lrow) * BK + kc * 32 + lquad * 8];
            #pragma unroll
            for (int i = 0; i < 4; i++)
                #pragma unroll
                for (int j = 0; j < 4; j++)
                    acc[i][j] = __builtin_amdgcn_mfma_f32_16x16x32_bf16(av[i], bvv[j], acc[i][j], 0, 0, 0);
        }
    }

    // ---- epilogue: stage to LDS [128][136], then coalesced ushort8 stores ----
    const float scale = (!vt && z == 0) ? QSCALE : 1.0f;
    __syncthreads();   // all MFMA reads of As/Bs done before overwrite
    #pragma unroll
    for (int j = 0; j < 4; j++) {
        int col = wn + j * 16 + lrow;
        float bn = vt ? 0.f : bias[n0 + col];
        #pragma unroll
        for (int i = 0; i < 4; i++) {
            #pragma unroll
            for (int rr = 0; rr < 4; ++rr) {
                int row = wm + i * 16 + lquad * 4 + rr;
                float v = vt ? (acc[i][j][rr] + bias[m0 + row])
                             : (acc[i][j][rr] + bn) * scale;
                SM[row * 136 + col] = f2u(v);
            }
        }
    }
    __syncthreads();
    #pragma unroll
    for (int it = 0; it < 8; ++it) {
        int idx = it * 256 + tid;          // 0..2047
        int row = idx >> 4, seg = idx & 15;
        u16x8 v8 = *(const u16x8*)&SM[row * 136 + seg * 8];
        if (!vt) {
            int gm = m0 + row;             // b, s
            int gc = n0 + seg * 8;         // h, d0
            int b = gm >> 11, s = gm & (SEQ - 1);
            int h = gc >> 6, d0 = gc & (HDIM - 1);
            u16* oz = QKw + (size_t)z * TSZ;
            *(u16x8*)&oz[(((size_t)(b * NHEAD + h)) * SEQ + s) * HDIM + d0] = v8;
        } else {
            int gm = m0 + row;             // h, d
            int h = gm >> 6, d = gm & (HDIM - 1);
            int gc = n0 + seg * 8;         // b, s0
            int b = gc >> 11, s0 = gc & (SEQ - 1);
            *(u16x8*)&Vtw[(((size_t)(b * NHEAD + h)) * HDIM + d) * SEQ + s0] = v8;
        }
    }
}

// ---------------------------------------------------------------------------
// Out projection: 64x128 tile (512 blocks), fp32 store. XCD swizzle.
// Epilogue: C staged to LDS [64][132] f32, then 8x float4 coalesced stores.
// ---------------------------------------------------------------------------
__launch_bounds__(256, 2)
__global__ void gemm_out(const u16* __restrict__ A, const u16* __restrict__ Wt,
                         const float* __restrict__ bias, float* __restrict__ out) {
    constexpr int BK = 64;
    __shared__ __attribute__((aligned(16))) u16 SM[64 * 132 * 2];  // 33.8 KB (f32 view)
    u16* As = SM;             // [64][64]
    u16* Bs = SM + 64 * BK;   // [128][64]

    const int tid = threadIdx.x;
    const int w = tid >> 6;
    const int lane = tid & 63;
    const int lrow = lane & 15, lquad = lane >> 4;
    const int L0 = blockIdx.y * 8 + blockIdx.x;      // dispatch-linear 0..511
    const int L = (L0 & 7) * 64 + (L0 >> 3);         // XCD-chunked, bijective on 512
    const int m0 = (L >> 3) * 64, n0 = (L & 7) * 128;

    frag_cd acc[2][4];
    #pragma unroll
    for (int i = 0; i < 2; i++)
        #pragma unroll
        for (int j = 0; j < 4; j++) acc[i][j] = (frag_cd){0.f, 0.f, 0.f, 0.f};

    const int wm = (w >> 1) * 32, wn = (w & 1) * 64;

    for (int k0 = 0; k0 < D_MODEL; k0 += BK) {
        __syncthreads();
        #pragma unroll
        for (int it = 0; it < 2; ++it) {
            int c = it * 256 + tid;
            int r = c >> 3, c8 = c & 7;
            const u16* ga = A + (size_t)(m0 + r) * D_MODEL + k0 + c8 * 8;
            char* la = (char*)As + (it * 256 + w * 64) * 16;
            __builtin_amdgcn_global_load_lds((const __attribute__((address_space(1))) void*)ga,
                                             (__attribute__((address_space(3))) void*)la, 16, 0, 0);
        }
        #pragma unroll
        for (int it = 0; it < 4; ++it) {
            int c = it * 256 + tid;
            int r = c >> 3, c8 = c & 7;
            const u16* gb = Wt + (size_t)(n0 + r) * D_MODEL + k0 + c8 * 8;
            char* lb = (char*)Bs + (it * 256 + w * 64) * 16;
            __builtin_amdgcn_global_load_lds((const __attribute__((address_space(1))) void*)gb,
                                             (__attribute__((address_space(3))) void*)lb, 16, 0, 0);
        }
        __syncthreads();

        #pragma unroll
        for (int kc = 0; kc < 2; ++kc) {
            frag_ab av[2], bvv[4];
            #pragma unroll
            for (int i = 0; i < 2; i++)
                av[i] = *(const frag_ab*)&As[(wm + i * 16 + lrow) * BK + kc * 32 + lquad * 8];
            #pragma unroll
            for (int j = 0; j < 4; j++)
                bvv[j] = *(const frag_ab*)&Bs[(wn + j * 16 + lrow) * BK + kc * 32 + lquad * 8];
            #pragma unroll
            for (int i = 0; i < 2; i++)
                #pragma unroll
                for (int j = 0; j < 4; j++)
                    acc[i][j] = __builtin_amdgcn_mfma_f32_16x16x32_bf16(av[i], bvv[j], acc[i][j], 0, 0, 0);
        }
    }

    // ---- epilogue: stage f32 to LDS [64][132], then coalesced float4 stores ----
    float* Tf = (float*)SM;
    __syncthreads();   // all MFMA reads done before overwrite
    #pragma unroll
    for (int j = 0; j < 4; j++) {
        int col = wn + j * 16 + lrow;
        float bvf = bias[n0 + col];
        #pragma unroll
        for (int i = 0; i < 2; i++)
            #pragma unroll
            for (int rr = 0; rr < 4; ++rr) {
                int row = wm + i * 16 + lquad * 4 + rr;
                Tf[row * 132 + col] = acc[i][j][rr] + bvf;
            }
    }
    __syncthreads();
    #pragma unroll
    for (int it = 0; it < 8; ++it) {
        int idx = it * 256 + tid;          // 0..2047
        int row = idx >> 5, seg = idx & 31;
        float4 v = *(const float4*)&Tf[row * 132 + seg * 4];
        *(float4*)&out[(size_t)(m0 + row) * D_MODEL + n0 + seg * 4] = v;
    }
}

// ---------------------------------------------------------------------------
// Attention (R15 structure, unchanged): grid (16,32) = 512 blocks, 512 thr =
// 8 waves (4 qg x 2 kh), each wave owns TWO 16-q fragments. Single-buffered
// 32KB staging (global_load_lds, source-side XOR swizzle); kh-partials
// combined additively via LDS; raw v_exp_f32; setprio; XCD swizzle.
// ---------------------------------------------------------------------------
__launch_bounds__(512, 4)
__global__ void attn_kernel(const u16* __restrict__ Q, const u16* __restrict__ K,
                            const u16* __restrict__ Vt, u16* __restrict__ O) {
    __shared__ __attribute__((aligned(16))) u16 SMEM[17664];  // 35.3 KB
    u16* Ks = SMEM;            // [128 keys][64 d], source-swizzled chunks
    u16* Vs = SMEM + 8192;     // [64 d][128 keys], source-swizzled chunks

    const int tid = threadIdx.x;
    const int w = tid >> 6;           // 8 waves
    const int lane = tid & 63;
    const int lrow = lane & 15, lquad = lane >> 4;
    const int qg = w & 3;             // q-group pair: groups qg, qg+4
    const int kh = w >> 2;            // key half: 0 -> keys [0,64), 1 -> [64,128)

    // XCD-chunked bijective block map: XCD x owns bh = 4x..4x+3, 16 q-tiles each
    const int L = blockIdx.y * 16 + blockIdx.x;      // dispatch-linear 0..511
    const int xcd = L & 7, off = L >> 3;             // off 0..63
    const int bh = xcd * 4 + (off >> 4);             // 0..31
    const int q0 = (off & 15) * 128;

    const size_t base = (size_t)bh * SEQ * HDIM;
    const u16* Qg = Q + base;
    const u16* Kg = K + base;
    const u16* Vg = Vt + base;  // [d][s]

    // Q as B-operand of 16x16x32: lane holds q = lrow, d = kc*32 + lquad*8 + j
    frag_ab qf[2][2];   // [group g][kc]
    #pragma unroll
    for (int g = 0; g < 2; ++g)
        #pragma unroll
        for (int kc = 0; kc < 2; ++kc)
            qf[g][kc] = *(const frag_ab*)&Qg[(size_t)(q0 + (qg + g * 4) * 16 + lrow) * HDIM + kc * 32 + lquad * 8];

    frag_cd accOT[2][4];   // [group][df]: partial O^T, lane q = lrow, d = df*16+lquad*4+i
    #pragma unroll
    for (int g = 0; g < 2; ++g)
        #pragma unroll
        for (int df = 0; df < 4; df++) accOT[g][df] = (frag_cd){0.f, 0.f, 0.f, 0.f};
    f32x2 la0 = (f32x2){0.f, 0.f}, la1 = (f32x2){0.f, 0.f};  // packed rowsum partials

    // ---- hoisted staging addresses (kt-invariant except constant stride) ----
    const int c0 = tid, c1 = 512 + tid;
    const u16* gk0 = Kg + ((c0 >> 3) * HDIM + (((c0 & 7) ^ ((c0 >> 3) & 7)) << 3));
    const u16* gk1 = Kg + ((c1 >> 3) * HDIM + (((c1 & 7) ^ ((c1 >> 3) & 7)) << 3));
    const u16* gv0 = Vg + ((size_t)(c0 >> 4) * SEQ + (((c0 & 15) ^ ((c0 >> 4) & 7)) << 3));
    const u16* gv1 = Vg + ((size_t)(c1 >> 4) * SEQ + (((c1 & 15) ^ ((c1 >> 4) & 7)) << 3));
    char* lk0 = (char*)Ks + (0 * 512 + w * 64) * 16;   // + implicit lane*16
    char* lk1 = (char*)Ks + (1 * 512 + w * 64) * 16;
    char* lv0 = (char*)Vs + (0 * 512 + w * 64) * 16;
    char* lv1 = (char*)Vs + (1 * 512 + w * 64) * 16;

    // ---- hoisted LDS fragment base pointers (kt-invariant) ----
    const u16* kb0 = Ks + (kh * 64 + lrow) * 64 + (((0 + lquad) ^ (lrow & 7)) << 3);
    const u16* kb1 = Ks + (kh * 64 + lrow) * 64 + (((4 + lquad) ^ (lrow & 7)) << 3);
    const u16* vb[4];
    #pragma unroll
    for (int cm = 0; cm < 4; ++cm) {
        const int gc = ((kh * 4 + cm) << 1) + (lquad >> 1);
        vb[cm] = Vs + lrow * 128 + ((gc ^ (lrow & 7)) << 3) + (lquad & 1) * 4;
    }

    for (int kt = 0; kt < SEQ / 128; ++kt) {
        __syncthreads();   // all reads of SMEM done
        __builtin_amdgcn_global_load_lds((const __attribute__((address_space(1))) void*)gk0,
                                         (__attribute__((address_space(3))) void*)lk0, 16, 0, 0);
        __builtin_amdgcn_global_load_lds((const __attribute__((address_space(1))) void*)gk1,
                                         (__attribute__((address_space(3))) void*)lk1, 16, 0, 0);
        __builtin_amdgcn_global_load_lds((const __attribute__((address_space(1))) void*)gv0,
                                         (__attribute__((address_space(3))) void*)lv0, 16, 0, 0);
        __builtin_amdgcn_global_load_lds((const __attribute__((address_space(1))) void*)gv1,
                                         (__attribute__((address_space(3))) void*)lv1, 16, 0, 0);
        gk0 += 128 * HDIM; gk1 += 128 * HDIM;   // next 128-key tile
        gv0 += 128;        gv1 += 128;
        __syncthreads();   // drain vmcnt, tile visible

        // this wave's 64 keys in 4 fragments of 16; each K/V read feeds 2 q-groups
        #pragma unroll
        for (int cm = 0; cm < 4; ++cm) {
            frag_cd sc0 = (frag_cd){0.f, 0.f, 0.f, 0.f};
            frag_cd sc1 = (frag_cd){0.f, 0.f, 0.f, 0.f};
            __builtin_amdgcn_s_setprio(1);
            {
                frag_ab kf0 = *(const frag_ab*)(kb0 + cm * 1024);
                frag_ab kf1 = *(const frag_ab*)(kb1 + cm * 1024);
                sc0 = __builtin_amdgcn_mfma_f32_16x16x32_bf16(kf0, qf[0][0], sc0, 0, 0, 0);
                sc1 = __builtin_amdgcn_mfma_f32_16x16x32_bf16(kf0, qf[1][0], sc1, 0, 0, 0);
                sc0 = __builtin_amdgcn_mfma_f32_16x16x32_bf16(kf1, qf[0][1], sc0, 0, 0, 0);
                sc1 = __builtin_amdgcn_mfma_f32_16x16x32_bf16(kf1, qf[1][1], sc1, 0, 0, 0);
            }
            __builtin_amdgcn_s_setprio(0);

            frag_s4 pk0, pk1;
            {
                float e0 = fexp2(sc0[0]), e1 = fexp2(sc0[1]);
                float e2 = fexp2(sc0[2]), e3 = fexp2(sc0[3]);
                f32x2 a = {e0, e1}, b2 = {e2, e3};
                la0 += a + b2;
                union { frag_s4 s; unsigned int u[2]; } pu;
                pu.u[0] = pkrn(e0, e1);
                pu.u[1] = pkrn(e2, e3);
                pk0 = pu.s;
            }
            {
                float e0 = fexp2(sc1[0]), e1 = fexp2(sc1[1]);
                float e2 = fexp2(sc1[2]), e3 = fexp2(sc1[3]);
                f32x2 a = {e0, e1}, b2 = {e2, e3};
                la1 += a + b2;
                union { frag_s4 s; unsigned int u[2]; } pu;
                pu.u[0] = pkrn(e0, e1);
                pu.u[1] = pkrn(e2, e3);
                pk1 = pu.s;
            }

            // O^T += V^T . P^T : each V fragment feeds both q-groups
            __builtin_amdgcn_s_setprio(1);
            {
                const u16* vp = vb[cm];
                #pragma unroll
                for (int df = 0; df < 4; df++) {
                    frag_s4 vf = *(const frag_s4*)(vp + df * 2048);
                    accOT[0][df] = __builtin_amdgcn_mfma_f32_16x16x16bf16_1k(vf, pk0, accOT[0][df], 0, 0, 0);
                    accOT[1][df] = __builtin_amdgcn_mfma_f32_16x16x16bf16_1k(vf, pk1, accOT[1][df], 0, 0, 0);
                }
            }
            __builtin_amdgcn_s_setprio(0);
        }
    }

    // rowsums: pack-halves + quad reduce (lanes lrow, +16, +32, +48 hold same q)
    float s0 = la0[0] + la0[1];
    s0 += __shfl_xor(s0, 16);
    s0 += __shfl_xor(s0, 32);
    float s1 = la1[0] + la1[1];
    s1 += __shfl_xor(s1, 16);
    s1 += __shfl_xor(s1, 32);

    // combine key-halves additively via LDS (reuse SMEM; stride 68 spreads banks)
    float* comb = (float*)SMEM;               // [128 q][68], 34816 B
    float* lsum = (float*)SMEM + 128 * 68;    // 128 f32
    __syncthreads();   // all tile reads done before overwrite
    if (kh) {
        #pragma unroll
        for (int g = 0; g < 2; ++g) {
            float* crow = comb + ((qg + g * 4) * 16 + lrow) * 68;
            #pragma unroll
            for (int df = 0; df < 4; df++)
                *(float4*)&crow[df * 16 + lquad * 4] =
                    (float4){accOT[g][df][0], accOT[g][df][1], accOT[g][df][2], accOT[g][df][3]};
        }
        if (lquad == 0) {
            lsum[qg * 16 + lrow] = s0;
            lsum[(qg + 4) * 16 + lrow] = s1;
        }
    }
    __syncthreads();
    if (!kh) {
        const int b = bh >> 4, h = bh & (NHEAD - 1);
        #pragma unroll
        for (int g = 0; g < 2; ++g) {
            const float* crow = comb + ((qg + g * 4) * 16 + lrow) * 68;
            #pragma unroll
            for (int df = 0; df < 4; df++) {
                float4 c = *(const float4*)&crow[df * 16 + lquad * 4];
                accOT[g][df][0] += c.x; accOT[g][df][1] += c.y;
                accOT[g][df][2] += c.z; accOT[g][df][3] += c.w;
            }
            float lacc = (g ? s1 : s0) + lsum[(qg + g * 4) * 16 + lrow];

            // epilogue: lane owns one q per group -> single reciprocal; b64 stores
            const int s = q0 + (qg + g * 4) * 16 + lrow;
            const float inv = 1.0f / lacc;
            u16* orow = O + ((size_t)(b * SEQ + s)) * D_MODEL + h * HDIM;
            #pragma unroll
            for (int df = 0; df < 4; df++) {
                union { unsigned int u[2]; ushort4 s4; } o;
                o.u[0] = pkrn(accOT[g][df][0] * inv, accOT[g][df][1] * inv);
                o.u[1] = pkrn(accOT[g][df][2] * inv, accOT[g][df][3] * inv);
                *(ushort4*)&orow[df * 16 + lquad * 4] = o.s4;
            }
        }
    }
}

// ---------------------------------------------------------------------------
// Workspace (u16 elems): xb [0,4M) | Wt 4 slabs [4M,8M) | Q,K [8M,16M)
//                        Vt [16M,20M) | attn-out [20M,24M)   = 48 MB
// ---------------------------------------------------------------------------
extern "C" void kernel_launch(void* const* d_in, const int* in_sizes, int n_in,
                              void* d_out, int out_size, void* d_ws, size_t ws_size,
                              hipStream_t stream) {
    const float* x  = (const float*)d_in[0];
    const float* Wq = (const float*)d_in[1];
    const float* bq = (const float*)d_in[2];
    const float* Wk = (const float*)d_in[3];
    const float* bk = (const float*)d_in[4];
    const float* Wv = (const float*)d_in[5];
    const float* bv = (const float*)d_in[6];
    const float* Wo = (const float*)d_in[7];
    const float* bo = (const float*)d_in[8];

    u16* ws = (u16*)d_ws;
    const size_t WSZ = (size_t)D_MODEL * D_MODEL;    // 1M elems
    const size_t TSZ = (size_t)MTOT * D_MODEL;       // 4M elems
    u16* xb  = ws;
    u16* Wt  = ws + 4 * WSZ;
    u16* QKw = ws + 8 * WSZ;        // Q slab 0, K slab 1
    u16* Vtw = QKw + 2 * TSZ;
    u16* Aw  = Vtw + TSZ;

    prep<<<dim3(32, 32, 5), dim3(32, 8), 0, stream>>>(Wq, Wk, Wv, Wo, x, Wt, xb);
    gemm_qkvt<<<dim3(768), 256, 0, stream>>>(xb, Wt, bq, bk, bv, QKw, Vtw);
    attn_kernel<<<dim3(16, 32), 512, 0, stream>>>(QKw, QKw + TSZ, Vtw, Aw);
    gemm_out<<<dim3(8, 64), 256, 0, stream>>>(Aw, Wt + 3 * WSZ, bo, (float*)d_out);
}